// Round 15
// baseline (1074.669 us; speedup 1.0000x reference)
//
#include <hip/hip_runtime.h>

#define BS 16
#define SEQ 1024
#define EMB 128
#define NHEAD 4
#define LN_EPS 1e-5f

typedef __attribute__((ext_vector_type(8))) short bf16x8;
typedef __attribute__((ext_vector_type(8))) _Float16 f16x8;
typedef __attribute__((ext_vector_type(4))) float f32x4;
typedef __attribute__((ext_vector_type(4))) unsigned short u16x4;
typedef __attribute__((ext_vector_type(4))) unsigned int u32x4;

__device__ __forceinline__ unsigned short f2b(float f) {
  union { float f; unsigned u; } v; v.f = f;
  unsigned r = v.u + 0x7fff + ((v.u >> 16) & 1);
  return (unsigned short)(r >> 16);
}
__device__ __forceinline__ float b2f(unsigned short u) {
  return __uint_as_float((unsigned)u << 16);
}
__device__ __forceinline__ unsigned short f2h(float f) {
  union { _Float16 h; unsigned short u; } v; v.h = (_Float16)f; return v.u;
}
// split x into hi+lo bf16 (3-term Markidis precision: rel err ~2^-17)
__device__ __forceinline__ void split2(float x, unsigned short& hi, unsigned short& lo) {
  unsigned short h = f2b(x);
  float hf = __uint_as_float((unsigned)h << 16);
  hi = h; lo = f2b(x - hf);
}
__device__ __forceinline__ float rsqrt_acc(float v) {
  float r = rsqrtf(v);
  return r * (1.5f - 0.5f * v * r * r);   // one Newton step -> ~f32-exact
}

// ---------------- weight prep: fragment-ordered 2-plane bf16 ----------------
__global__ void k_prep_fragT(const float* __restrict__ in, unsigned short* __restrict__ out,
                             size_t PL, int L, int Kin, int Nin, int N, int K) {
  int idx = blockIdx.x * 256 + threadIdx.x;
  int nblk = (N >> 4) * (K >> 5);
  int total = L * N * K;
  if (idx >= total) return;
  int e = idx & 7;
  int lane = (idx >> 3) & 63;
  int blk = (idx >> 9) % nblk;
  int l = idx / (512 * nblk);
  int nb = blk % (N >> 4), kc = blk / (N >> 4);
  int n = nb * 16 + (lane & 15);
  int k = kc * 32 + (lane >> 4) * 8 + e;
  float v = (k < Kin && n < Nin) ? in[(size_t)l * Kin * Nin + (size_t)k * Nin + n] : 0.f;
  unsigned short hi, lo; split2(v, hi, lo);
  out[idx] = hi; out[PL + idx] = lo;
}

// qvW frag: N=512, K=128; n<256 q side (h=n>>6,d=n&63, d63 zero), else v side
__global__ void k_prep_qvfrag(const float* __restrict__ qW, const float* __restrict__ vW,
                              unsigned short* __restrict__ out, size_t PL) {
  int idx = blockIdx.x * 256 + threadIdx.x;
  int total = 11 * 512 * 128;
  if (idx >= total) return;
  int e = idx & 7;
  int lane = (idx >> 3) & 63;
  int blk = (idx >> 9) & 127;       // kc*32 + nb
  int l = idx >> 16;
  int nb = blk & 31, kc = blk >> 5;
  int n = nb * 16 + (lane & 15);
  int k = kc * 32 + (lane >> 4) * 8 + e;
  float v = 0.f;
  if (n < 256) {
    int hh = n >> 6, d = n & 63;
    if (d < 63 && k >= 64 && k < 127) v = qW[(size_t)l * 63 * 252 + (size_t)(k - 64) * 252 + hh * 63 + d];
  } else {
    int n2 = n - 256, hh = n2 >> 6, d = n2 & 63;
    if (d < 63 && k < 63) v = vW[(size_t)l * 63 * 252 + (size_t)k * 252 + hh * 63 + d];
  }
  unsigned short hi, lo; split2(v, hi, lo);
  out[idx] = hi; out[PL + idx] = lo;
}

// last-layer qkv frag: N=1536, K=128
__global__ void k_prep_lastfrag(const float* __restrict__ qW, const float* __restrict__ kW,
                                const float* __restrict__ vW,
                                unsigned short* __restrict__ out, size_t PL) {
  int idx = blockIdx.x * 256 + threadIdx.x;
  int total = 1536 * 128;
  if (idx >= total) return;
  int e = idx & 7;
  int lane = (idx >> 3) & 63;
  int blk = idx >> 9;               // kc*96 + nb
  int nb = blk % 96, kc = blk / 96;
  int n = nb * 16 + (lane & 15);
  int k = kc * 32 + (lane >> 4) * 8 + e;
  int tsel = n >> 9, n2 = n & 511;
  const float* W = tsel == 0 ? qW : (tsel == 1 ? kW : vW);
  float v = W[(size_t)k * 512 + n2];
  unsigned short hi, lo; split2(v, hi, lo);
  out[idx] = hi; out[PL + idx] = lo;
}

// ---------------- combine + read_in (2-plane bf16 state only) ----------------
__global__ void k_combine_readin(const float* __restrict__ xs, const float* __restrict__ ys,
                                 const float* __restrict__ W, const float* __restrict__ bias,
                                 unsigned short* __restrict__ Hbf, size_t hbPl,
                                 unsigned short* __restrict__ Hh) {
  int blk = blockIdx.x;            // b*1024 + t
  int b = blk >> 10, t = blk & 1023, p = t >> 1;
  __shared__ float zs[64];
  int tid = threadIdx.x;           // 128
  if (tid < 64) {
    float v;
    if (tid < 63) v = xs[((size_t)b * 512 + p) * 63 + tid];
    else v = (t & 1) ? ys[(size_t)b * 512 + p] : 0.f;
    zs[tid] = v;
  }
  __syncthreads();
  float acc = bias[tid];
  #pragma unroll 8
  for (int d = 0; d < 64; ++d) acc += zs[d] * W[d * 128 + tid];
  size_t o = (size_t)blk * 128 + tid;
  unsigned short hi, lo; split2(acc, hi, lo);
  Hbf[o] = hi; Hbf[hbPl + o] = lo;
  if (tid < 64) Hh[(size_t)blk * 64 + tid] = f2h(acc);  // fp16 K image (dims 0..63)
}

// ---------------- split-precision MFMA GEMM: A LDS-staged, B fragment-ordered ----------------
// MODE 2: last qkv frag fp16; MODE 3: qv frag fp16 (layer 0 only)
template<int MODE, bool RELU>
__global__ __launch_bounds__(256) void k_gemm(
    const unsigned short* __restrict__ A, size_t aPl,
    const unsigned short* __restrict__ BT, size_t bPl, const float* __restrict__ bias,
    int N,
    unsigned short* __restrict__ out0,
    unsigned short* __restrict__ out1,
    unsigned short* __restrict__ out2) {
  extern __shared__ unsigned short lds[];   // A 2 planes [64][136] = 34816 B; tile reuse
  int tid = threadIdx.x;
  int wid = tid >> 6, lane = tid & 63;
  int lr = lane & 15, lg = lane >> 4;
  int row0g = blockIdx.x * 64;
  int n0 = blockIdx.y * 64;
  unsigned short* Ah = lds;
  unsigned short* Al = Ah + 64 * 136;
  {
    const unsigned short* gA = A + (size_t)row0g * 128;
    const unsigned short* srcs[2] = { gA, gA + aPl };
    unsigned short* dsts[2] = { Ah, Al };
    #pragma unroll
    for (int p = 0; p < 2; ++p)
      #pragma unroll
      for (int it = 0; it < 4; ++it) {
        int e = it * 2048 + tid * 8;
        bf16x8 v = *reinterpret_cast<const bf16x8*>(srcs[p] + e);
        *reinterpret_cast<bf16x8*>(dsts[p] + (e >> 7) * 136 + (e & 127)) = v;
      }
  }
  __syncthreads();
  bf16x8 afh[4], afl[4];
  #pragma unroll
  for (int kf = 0; kf < 4; ++kf) {
    int o = (wid * 16 + lr) * 136 + kf * 32 + lg * 8;
    afh[kf] = *reinterpret_cast<const bf16x8*>(Ah + o);
    afl[kf] = *reinterpret_cast<const bf16x8*>(Al + o);
  }
  f32x4 acc[4] = {};
  int nhw = N >> 4;
  #pragma unroll
  for (int nf = 0; nf < 4; ++nf) {
    #pragma unroll
    for (int kf = 0; kf < 4; ++kf) {
      size_t bo = ((size_t)kf * nhw + (n0 >> 4) + nf) * 512 + lane * 8;
      bf16x8 bh = *reinterpret_cast<const bf16x8*>(BT + bo);
      bf16x8 bl = *reinterpret_cast<const bf16x8*>(BT + bPl + bo);
      acc[nf] = __builtin_amdgcn_mfma_f32_16x16x32_bf16(afh[kf], bh, acc[nf], 0, 0, 0);
      acc[nf] = __builtin_amdgcn_mfma_f32_16x16x32_bf16(afl[kf], bh, acc[nf], 0, 0, 0);
      acc[nf] = __builtin_amdgcn_mfma_f32_16x16x32_bf16(afh[kf], bl, acc[nf], 0, 0, 0);
    }
  }
  __syncthreads();   // done with staged A; reuse lds for the output tile
  #pragma unroll
  for (int nf = 0; nf < 4; ++nf) {
    int c = n0 + nf * 16 + lr;
    float bv = bias ? bias[c] : 0.f;
    #pragma unroll
    for (int r = 0; r < 4; ++r) {
      float v = acc[nf][r] + bv;
      if (RELU) v = fmaxf(v, 0.f);
      int rL = wid * 16 + lg * 4 + r, cL = nf * 16 + lr;
      ((unsigned short(*)[66])lds)[rL][cL] = f2h(v);
    }
  }
  __syncthreads();
  int u = tid * 2;
  int lane2 = u >> 3, e0 = u & 7;
  if (MODE == 2) {
    unsigned short (*t16)[66] = (unsigned short(*)[66])lds;
    int b = row0g >> 10, t0 = row0g & 1023;
    int tsel = n0 >> 9, c2b = n0 & 511, hh = c2b >> 7, dbase = c2b & 127;
    size_t bh = (size_t)b * NHEAD + hh;
    if (tsel < 2) {
      unsigned short* base = tsel ? out1 : out0;
      int tb0 = t0 >> 4, kc0 = dbase >> 5;
      #pragma unroll
      for (int fb = 0; fb < 8; ++fb) {
        int tbl = fb >> 1, kcl = fb & 1;
        int t_l = tbl * 16 + (lane2 & 15);
        int c_l = kcl * 32 + ((lane2 >> 4) << 3) + e0;
        size_t dst = ((bh * 64 + tb0 + tbl) * 4 + kc0 + kcl) * 512 + lane2 * 8 + e0;
        base[dst] = t16[t_l][c_l];
        base[dst + 1] = t16[t_l][c_l + 1];
      }
    } else {
      int db0 = dbase >> 4, jc0 = t0 >> 5;
      #pragma unroll
      for (int fb = 0; fb < 8; ++fb) {
        int dbl = fb >> 1, jcl = fb & 1;
        int c_l = dbl * 16 + (lane2 & 15);
        int t_l = jcl * 32 + ((lane2 >> 4) << 3) + e0;
        size_t dst = ((bh * 8 + db0 + dbl) * 32 + jc0 + jcl) * 512 + lane2 * 8 + e0;
        out2[dst] = t16[t_l][c_l];
        out2[dst + 1] = t16[t_l + 1][c_l];
      }
    }
  } else {  // MODE 3
    unsigned short (*t16)[66] = (unsigned short(*)[66])lds;
    int b = row0g >> 10, t0 = row0g & 1023;
    if (n0 < 256) {
      size_t bh = (size_t)b * NHEAD + (n0 >> 6);
      int tb0 = t0 >> 4;
      #pragma unroll
      for (int fb = 0; fb < 8; ++fb) {
        int tbl = fb >> 1, kcl = fb & 1;
        int t_l = tbl * 16 + (lane2 & 15);
        int c_l = kcl * 32 + ((lane2 >> 4) << 3) + e0;
        size_t dst = ((bh * 64 + tb0 + tbl) * 2 + kcl) * 512 + lane2 * 8 + e0;
        out0[dst] = t16[t_l][c_l];
        out0[dst + 1] = t16[t_l][c_l + 1];
      }
    } else {
      size_t bh = (size_t)b * NHEAD + ((n0 - 256) >> 6);
      int jc0 = t0 >> 5;
      #pragma unroll
      for (int fb = 0; fb < 8; ++fb) {
        int dbl = fb >> 1, jcl = fb & 1;
        int c_l = dbl * 16 + (lane2 & 15);
        int t_l = jcl * 32 + ((lane2 >> 4) << 3) + e0;
        size_t dst = ((bh * 4 + dbl) * 32 + jc0 + jcl) * 512 + lane2 * 8 + e0;
        out1[dst] = t16[t_l][c_l];
        out1[dst + 1] = t16[t_l + 1][c_l];
      }
    }
  }
}

// ---------------- attention v7 (layers 0-10, D=64); 2-plane state in/out ----------------
__global__ __launch_bounds__(512) void k_attn_v7(
    const unsigned short* __restrict__ q,      // fp16 frag [bh][tb 64][kc 2][512]
    const unsigned short* __restrict__ Hh,     // fp16 [b][t][64]
    const unsigned short* __restrict__ vT,     // fp16 frag [bh][db 4][jc 32][512]
    const float* __restrict__ head_mask,
    const unsigned short* __restrict__ HbfIn, unsigned short* __restrict__ HbfOut, size_t hbPl,
    const float* __restrict__ g, const float* __restrict__ bta) {
  extern __shared__ char sh[];
  int bid = blockIdx.x;
  int xcd = bid & 7, u = bid >> 3;
  int b = xcd * 2 + (u >> 4);
  int pidx = u & 15;
  int tid = threadIdx.x;
  int wid = tid >> 6, lane = tid & 63;
  int h = wid & 3, grp = wid >> 2;
  int lr = lane & 15, lg = lane >> 4;
  int i0t[2] = { pidx * 32, (31 - pidx) * 32 };
  int NSS = (33 - pidx) >> 1;

  const char* gK = (const char*)(Hh + (size_t)b * SEQ * 64);
  char* KB = sh;
  unsigned short* sw = (unsigned short*)(sh + 16384 + wid * 2560);

  const unsigned short* qh = q + (size_t)(b * NHEAD + h) * 65536;
  const unsigned short* vh = vT + (size_t)(b * NHEAD + h) * 65536;

  f16x8 qf[2][2][2];
  #pragma unroll
  for (int t = 0; t < 2; ++t)
    #pragma unroll
    for (int mf = 0; mf < 2; ++mf)
      #pragma unroll
      for (int kf = 0; kf < 2; ++kf)
        qf[t][mf][kf] = *reinterpret_cast<const f16x8*>(
            qh + ((((i0t[t] >> 4) + mf) * 2 + kf) << 9) + lane * 8);
  f32x4 oacc[2][2][4] = {};

  u32x4 sreg;
  auto SLOAD = [&](int ss) {
    sreg = *reinterpret_cast<const u32x4*>(gK + (size_t)ss * 8192 + tid * 16);
  };
  auto SWRITE = [&](int buf) {
    int row = tid >> 3, colb = (tid & 7) * 16;
    *reinterpret_cast<u32x4*>(KB + buf * 8192 + row * 128 + (colb ^ ((row & 7) << 4))) = sreg;
  };

  SLOAD(0); SWRITE(0);
  __syncthreads();

  for (int ss = 0; ss < NSS; ++ss) {
    int cur = ss & 1;
    bool more = (ss + 1 < NSS);
    if (more) SLOAD(ss + 1);
    int js = ss * 64 + grp * 32;
    if (js < i0t[1] + 32) {
      f16x8 vch[4];
      #pragma unroll
      for (int nf = 0; nf < 4; ++nf)
        vch[nf] = *reinterpret_cast<const f16x8*>(vh + ((nf * 32 + (js >> 5)) << 9) + lane * 8);
      f16x8 kfr[2][2];
      #pragma unroll
      for (int nf2 = 0; nf2 < 2; ++nf2)
        #pragma unroll
        for (int kf = 0; kf < 2; ++kf) {
          int row = grp * 32 + nf2 * 16 + lr;
          int colb = kf * 64 + lg * 16;
          kfr[nf2][kf] = *reinterpret_cast<const f16x8*>(
              KB + cur * 8192 + row * 128 + (colb ^ ((row & 7) << 4)));
        }
      #pragma unroll
      for (int t = 0; t < 2; ++t) {
        if (js < i0t[t] + 32) {
          #pragma unroll
          for (int nf2 = 0; nf2 < 2; ++nf2) {
            #pragma unroll
            for (int mf = 0; mf < 2; ++mf) {
              f32x4 sacc = {};
              #pragma unroll
              for (int kf = 0; kf < 2; ++kf)
                sacc = __builtin_amdgcn_mfma_f32_16x16x32_f16(qf[t][mf][kf], kfr[nf2][kf], sacc, 0, 0, 0);
              #pragma unroll
              for (int r = 0; r < 4; ++r) {
                int i = i0t[t] + mf * 16 + lg * 4 + r;
                int j = js + nf2 * 16 + lr;
                float v = (j <= i) ? fmaxf(sacc[r], 0.f) : 0.f;
                sw[(mf * 16 + lg * 4 + r) * 40 + nf2 * 16 + lr] = f2h(v);
              }
            }
          }
          asm volatile("s_waitcnt lgkmcnt(0)" ::: "memory");
          __builtin_amdgcn_sched_barrier(0);
          #pragma unroll
          for (int mf = 0; mf < 2; ++mf) {
            f16x8 sf = *reinterpret_cast<const f16x8*>(&sw[(mf * 16 + lr) * 40 + lg * 8]);
            #pragma unroll
            for (int nf = 0; nf < 4; ++nf)
              oacc[t][mf][nf] = __builtin_amdgcn_mfma_f32_16x16x32_f16(sf, vch[nf], oacc[t][mf][nf], 0, 0, 0);
          }
        }
      }
    }
    if (more) SWRITE(cur ^ 1);
    __syncthreads();
  }

  float hm = head_mask[h];
  float hm3 = hm * hm * hm;
  float* f8 = (float*)sh;
  for (int t = 0; t < 2; ++t) {
    #pragma unroll
    for (int mf = 0; mf < 2; ++mf)
      #pragma unroll
      for (int nf = 0; nf < 4; ++nf)
        #pragma unroll
        for (int r = 0; r < 4; ++r)
          f8[wid * 2048 + (mf * 16 + lg * 4 + r) * 64 + nf * 16 + lr] = oacc[t][mf][nf][r] * hm3;
    __syncthreads();
    for (int idx = tid; idx < 8192; idx += 512) f8[idx] += f8[idx + 8192];
    __syncthreads();
    for (int idx = tid; idx < 4096; idx += 512) f8[idx] += f8[idx + 4096];
    __syncthreads();
    for (int idx = tid; idx < 2048; idx += 512) {
      int rr = idx >> 6;
      f8[idx] = (f8[idx] + f8[idx + 2048]) / (float)(i0t[t] + rr + 1);
    }
    __syncthreads();
    for (int rl = 0; rl < 4; ++rl) {
      int rr = wid * 4 + rl;
      size_t row = ((size_t)b * SEQ + i0t[t] + rr) * EMB;
      int c0 = lane, c1 = lane + 64;
      float x0 = b2f(HbfIn[row + c0]) + b2f(HbfIn[hbPl + row + c0]);
      float x1 = b2f(HbfIn[row + c1]) + b2f(HbfIn[hbPl + row + c1]) + f8[rr * 64 + lane];
      float s1 = x0 + x1, s2 = x0 * x0 + x1 * x1;
      #pragma unroll
      for (int off = 1; off < 64; off <<= 1) {
        s1 += __shfl_xor(s1, off);
        s2 += __shfl_xor(s2, off);
      }
      float mu = s1 * (1.f / 128.f);
      float var = s2 * (1.f / 128.f) - mu * mu;
      float rs = rsqrt_acc(var + LN_EPS);
      float y0 = (x0 - mu) * rs * g[c0] + bta[c0];
      float y1 = (x1 - mu) * rs * g[c1] + bta[c1];
      unsigned short h0, l0, h1, l1; split2(y0, h0, l0); split2(y1, h1, l1);
      HbfOut[row + c0] = h0; HbfOut[hbPl + row + c0] = l0;
      HbfOut[row + c1] = h1; HbfOut[hbPl + row + c1] = l1;
    }
    __syncthreads();
  }
}

// ---------------- fused attention (+LN1), last layer (DHEAD=128); 2-plane state ----------------
__global__ __launch_bounds__(512) void k_attn_fused(
    const unsigned short* __restrict__ q,      // fp16 frag [bh][tb 64][kc 4][512]
    const unsigned short* __restrict__ kbuf,   // fp16 frag [bh][tb 64][kc 4][512]
    const unsigned short* __restrict__ vT,     // fp16 frag [bh][db 8][jc 32][512]
    const float* __restrict__ head_mask,
    const unsigned short* __restrict__ HbfIn, unsigned short* __restrict__ HbfOut, size_t hbPl,
    const float* __restrict__ g, const float* __restrict__ bta) {
  constexpr int KF = 4, NFO = 8;
  constexpr int NT = SEQ / 32;
  extern __shared__ char sh[];      // attn: sw [0,20480); epilogue f8 [0,65536)
  int bid = blockIdx.x;
  int xcd = bid & 7, u = bid >> 3;
  int b = xcd * 2 + (u >> 4);
  int pidx = u & 15;
  int tid = threadIdx.x;
  int wid = tid >> 6, lane = tid & 63;
  int h = wid & 3, grp = wid >> 2;
  int lr = lane & 15, lg = lane >> 4;
  unsigned short* sw = (unsigned short*)(sh + wid * 2560);
  const unsigned short* qh = q + (size_t)(b * NHEAD + h) * 131072;
  const unsigned short* kh = kbuf + (size_t)(b * NHEAD + h) * 131072;
  const unsigned short* vh = vT + (size_t)(b * NHEAD + h) * 131072;
  float hm = head_mask[h];
  float hm3 = hm * hm * hm;

  for (int s = 0; s < 2; ++s) {
    int tile = (s == 0) ? pidx : (NT - 1 - pidx);
    int i0 = tile * 32;
    f16x8 qf[2][KF];
    #pragma unroll
    for (int mf = 0; mf < 2; ++mf)
      #pragma unroll
      for (int kf = 0; kf < KF; ++kf)
        qf[mf][kf] = *reinterpret_cast<const f16x8*>(
            qh + ((((i0 >> 4) + mf) * 4 + kf) << 9) + lane * 8);
    f32x4 oacc[2][NFO] = {};
    int jend = i0 + 32;
    for (int j0 = grp * 32; j0 < jend; j0 += 64) {
      f16x8 vch[NFO];
      #pragma unroll
      for (int nf = 0; nf < NFO; ++nf)
        vch[nf] = *reinterpret_cast<const f16x8*>(vh + ((nf * 32 + (j0 >> 5)) << 9) + lane * 8);
      #pragma unroll
      for (int nf2 = 0; nf2 < 2; ++nf2) {
        f16x8 kfr[KF];
        #pragma unroll
        for (int kf = 0; kf < KF; ++kf)
          kfr[kf] = *reinterpret_cast<const f16x8*>(
              kh + ((((j0 >> 4) + nf2) * 4 + kf) << 9) + lane * 8);
        #pragma unroll
        for (int mf = 0; mf < 2; ++mf) {
          f32x4 sacc = {};
          #pragma unroll
          for (int kf = 0; kf < KF; ++kf)
            sacc = __builtin_amdgcn_mfma_f32_16x16x32_f16(qf[mf][kf], kfr[kf], sacc, 0, 0, 0);
          #pragma unroll
          for (int r = 0; r < 4; ++r) {
            int i = i0 + mf * 16 + lg * 4 + r;
            int j = j0 + nf2 * 16 + lr;
            float v = (j <= i) ? fmaxf(sacc[r], 0.f) : 0.f;
            sw[(mf * 16 + lg * 4 + r) * 40 + nf2 * 16 + lr] = f2h(v);
          }
        }
      }
      asm volatile("s_waitcnt lgkmcnt(0)" ::: "memory");
      __builtin_amdgcn_sched_barrier(0);
      #pragma unroll
      for (int mf = 0; mf < 2; ++mf) {
        f16x8 sf = *reinterpret_cast<const f16x8*>(&sw[(mf * 16 + lr) * 40 + lg * 8]);
        #pragma unroll
        for (int nf = 0; nf < NFO; ++nf)
          oacc[mf][nf] = __builtin_amdgcn_mfma_f32_16x16x32_f16(sf, vch[nf], oacc[mf][nf], 0, 0, 0);
      }
    }
    // ---- parallel tree head-sum: f8[4 head-regions][32][128] ----
    float* f8 = (float*)sh;
    __syncthreads();
    if (wid < 4) {
      #pragma unroll
      for (int mf = 0; mf < 2; ++mf)
        #pragma unroll
        for (int nf = 0; nf < NFO; ++nf)
          #pragma unroll
          for (int r = 0; r < 4; ++r)
            f8[(wid & 3) * 4096 + (mf * 16 + lg * 4 + r) * 128 + nf * 16 + lr] = oacc[mf][nf][r] * hm3;
    }
    __syncthreads();
    if (wid >= 4) {
      #pragma unroll
      for (int mf = 0; mf < 2; ++mf)
        #pragma unroll
        for (int nf = 0; nf < NFO; ++nf)
          #pragma unroll
          for (int r = 0; r < 4; ++r)
            f8[(wid & 3) * 4096 + (mf * 16 + lg * 4 + r) * 128 + nf * 16 + lr] += oacc[mf][nf][r] * hm3;
    }
    __syncthreads();
    for (int idx = tid; idx < 8192; idx += 512) f8[idx] += f8[idx + 8192];
    __syncthreads();
    for (int idx = tid; idx < 4096; idx += 512) {
      int rr = idx >> 7;
      f8[idx] = (f8[idx] + f8[idx + 4096]) / (float)(i0 + rr + 1);
    }
    __syncthreads();
    for (int rl = 0; rl < 4; ++rl) {
      int rr = wid * 4 + rl;
      size_t row = ((size_t)b * SEQ + i0 + rr) * EMB;
      int c0 = lane, c1 = lane + 64;
      float x0 = b2f(HbfIn[row + c0]) + b2f(HbfIn[hbPl + row + c0]) + f8[rr * 128 + c0];
      float x1 = b2f(HbfIn[row + c1]) + b2f(HbfIn[hbPl + row + c1]) + f8[rr * 128 + c1];
      float s1 = x0 + x1, s2 = x0 * x0 + x1 * x1;
      #pragma unroll
      for (int off = 1; off < 64; off <<= 1) {
        s1 += __shfl_xor(s1, off);
        s2 += __shfl_xor(s2, off);
      }
      float mu = s1 * (1.f / 128.f);
      float var = s2 * (1.f / 128.f) - mu * mu;
      float rs = rsqrt_acc(var + LN_EPS);
      float y0 = (x0 - mu) * rs * g[c0] + bta[c0];
      float y1 = (x1 - mu) * rs * g[c1] + bta[c1];
      unsigned short h0, l0, h1, l1; split2(y0, h0, l0); split2(y1, h1, l1);
      HbfOut[row + c0] = h0; HbfOut[hbPl + row + c0] = l0;
      HbfOut[row + c1] = h1; HbfOut[hbPl + row + c1] = l1;
    }
    __syncthreads();
  }
}

// ---------------- fused MLP (mlp1+mlp2+residual+LN2 [+next-layer qv projection]) ----------------
// MM=0: +qv for next layer; MM=1: plain; MM=2: last (writes f32 H).
// 16 rows/block, grid 1024, 4 waves, LDS 40960 B (4 blocks/CU).
template<int MM>
__global__ __launch_bounds__(256) void k_mlpf(
    const unsigned short* __restrict__ A, size_t aPl,      // Hbf2 2-plane (post-LN1 y)
    const unsigned short* __restrict__ W1, size_t w1Pl, const float* __restrict__ b1,
    const unsigned short* __restrict__ W2, size_t w2Pl, const float* __restrict__ b2,
    unsigned short* __restrict__ HbfOut, size_t hbPl,
    unsigned short* __restrict__ Hh, float* __restrict__ Hst,
    const float* __restrict__ g, const float* __restrict__ bta,
    const unsigned short* __restrict__ QW, size_t qwPl,
    unsigned short* __restrict__ qOut, unsigned short* __restrict__ vOut) {
  extern __shared__ unsigned short mlds[];
  unsigned short* As = mlds;              // 4096 u16 (2 planes x [16][128], XOR-swizzled)
  unsigned short* Mid = mlds + 4096;      // 16384 u16 (2 planes frag-ordered)
  float* yb = (float*)Mid;                // aliases Mid [0,4224) u16-equiv
  unsigned short* st = Mid + 8192;        // qv staging [16][512] (aliases Mid lo plane)
  int tid = threadIdx.x;
  int wid = tid >> 6, lane = tid & 63;
  int lr = lane & 15, lg = lane >> 4;
  int row0g = blockIdx.x * 16;
  {
    const unsigned short* gA = A + (size_t)row0g * 128;
    int row = tid >> 4;
    int sc = ((tid & 15) * 8) ^ ((row & 7) << 3);
    *reinterpret_cast<bf16x8*>(As + row * 128 + sc) =
        *reinterpret_cast<const bf16x8*>(gA + tid * 8);
    *reinterpret_cast<bf16x8*>(As + 2048 + row * 128 + sc) =
        *reinterpret_cast<const bf16x8*>(gA + aPl + tid * 8);
  }
  __syncthreads();
  bf16x8 afh[4], afl[4];
  #pragma unroll
  for (int kf = 0; kf < 4; ++kf) {
    int o = lr * 128 + ((kf * 32 + lg * 8) ^ ((lr & 7) << 3));
    afh[kf] = *reinterpret_cast<const bf16x8*>(As + o);
    afl[kf] = *reinterpret_cast<const bf16x8*>(As + 2048 + o);
  }
  // ---- mlp1: wave does n-tiles wid*8..+7; 2-deep W1 prefetch ----
  bf16x8 cwh[4], cwl[4], nwh[4], nwl[4];
  #pragma unroll
  for (int kf = 0; kf < 4; ++kf) {
    size_t bo = ((size_t)kf * 32 + wid * 8) * 512 + lane * 8;
    cwh[kf] = *reinterpret_cast<const bf16x8*>(W1 + bo);
    cwl[kf] = *reinterpret_cast<const bf16x8*>(W1 + w1Pl + bo);
  }
  #pragma unroll
  for (int j = 0; j < 8; ++j) {
    int ntile = wid * 8 + j;
    if (j < 7) {
      #pragma unroll
      for (int kf = 0; kf < 4; ++kf) {
        size_t bo = ((size_t)kf * 32 + ntile + 1) * 512 + lane * 8;
        nwh[kf] = *reinterpret_cast<const bf16x8*>(W1 + bo);
        nwl[kf] = *reinterpret_cast<const bf16x8*>(W1 + w1Pl + bo);
      }
    }
    f32x4 acc = {};
    #pragma unroll
    for (int kf = 0; kf < 4; ++kf) {
      acc = __builtin_amdgcn_mfma_f32_16x16x32_bf16(afh[kf], cwh[kf], acc, 0, 0, 0);
      acc = __builtin_amdgcn_mfma_f32_16x16x32_bf16(afl[kf], cwh[kf], acc, 0, 0, 0);
      acc = __builtin_amdgcn_mfma_f32_16x16x32_bf16(afh[kf], cwl[kf], acc, 0, 0, 0);
    }
    int c = ntile * 16 + lr;
    float bv = b1[c];
    int kc = c >> 5, sub = ((c & 31) >> 3) * 128 + (c & 7);
    #pragma unroll
    for (int r = 0; r < 4; ++r) {
      float v = fmaxf(acc[r] + bv, 0.f);
      unsigned short hi, lo; split2(v, hi, lo);
      int ma = kc * 512 + sub + (lg * 4 + r) * 8;
      Mid[ma] = hi;
      Mid[8192 + ma] = lo;
    }
    if (j < 7) {
      #pragma unroll
      for (int kf = 0; kf < 4; ++kf) { cwh[kf] = nwh[kf]; cwl[kf] = nwl[kf]; }
    }
  }
  __syncthreads();
  // ---- mlp2: wave does n-tiles wid*2, wid*2+1; 2-deep W2 prefetch; Mid reads linear ----
  f32x4 acc2[2] = {};
  bf16x8 c2h[2], c2l[2], n2h[2], n2l[2];
  #pragma unroll
  for (int j = 0; j < 2; ++j) {
    size_t bo = (size_t)(wid * 2 + j) * 512 + lane * 8;
    c2h[j] = *reinterpret_cast<const bf16x8*>(W2 + bo);
    c2l[j] = *reinterpret_cast<const bf16x8*>(W2 + w2Pl + bo);
  }
  #pragma unroll
  for (int kc = 0; kc < 16; ++kc) {
    if (kc < 15) {
      #pragma unroll
      for (int j = 0; j < 2; ++j) {
        size_t bo = ((size_t)(kc + 1) * 8 + wid * 2 + j) * 512 + lane * 8;
        n2h[j] = *reinterpret_cast<const bf16x8*>(W2 + bo);
        n2l[j] = *reinterpret_cast<const bf16x8*>(W2 + w2Pl + bo);
      }
    }
    int o = kc * 512 + lane * 8;
    bf16x8 amh = *reinterpret_cast<const bf16x8*>(Mid + o);
    bf16x8 aml = *reinterpret_cast<const bf16x8*>(Mid + 8192 + o);
    #pragma unroll
    for (int j = 0; j < 2; ++j) {
      acc2[j] = __builtin_amdgcn_mfma_f32_16x16x32_bf16(amh, c2h[j], acc2[j], 0, 0, 0);
      acc2[j] = __builtin_amdgcn_mfma_f32_16x16x32_bf16(aml, c2h[j], acc2[j], 0, 0, 0);
      acc2[j] = __builtin_amdgcn_mfma_f32_16x16x32_bf16(amh, c2l[j], acc2[j], 0, 0, 0);
    }
    if (kc < 15) {
      c2h[0] = n2h[0]; c2h[1] = n2h[1];
      c2l[0] = n2l[0]; c2l[1] = n2l[1];
    }
  }
  __syncthreads();   // all waves done reading Mid (yb aliases it)
  // ---- residual (reconstructed from swizzled As) into yb ----
  #pragma unroll
  for (int j = 0; j < 2; ++j) {
    int c = (wid * 2 + j) * 16 + lr;
    float bv = b2[c];
    #pragma unroll
    for (int r = 0; r < 4; ++r) {
      int row = lg * 4 + r;
      int sc = c ^ ((row & 7) << 3);
      float yres = b2f(As[row * 128 + sc]) + b2f(As[2048 + row * 128 + sc]);
      yb[row * 132 + c] = acc2[j][r] + bv + yres;
    }
  }
  __syncthreads();
  // ---- LN2: wave owns rows wid*4 .. wid*4+3; y written back to yb for qv phase ----
  for (int rl = 0; rl < 4; ++rl) {
    int row = wid * 4 + rl;
    size_t gro = (size_t)(row0g + row) * EMB;
    int c0 = lane, c1 = lane + 64;
    float x0 = yb[row * 132 + c0];
    float x1 = yb[row * 132 + c1];
    float s1 = x0 + x1, s2 = x0 * x0 + x1 * x1;
    #pragma unroll
    for (int off = 1; off < 64; off <<= 1) {
      s1 += __shfl_xor(s1, off);
      s2 += __shfl_xor(s2, off);
    }
    float mu = s1 * (1.f / 128.f);
    float var = s2 * (1.f / 128.f) - mu * mu;
    float rs = rsqrt_acc(var + LN_EPS);
    float y0 = (x0 - mu) * rs * g[c0] + bta[c0];
    float y1 = (x1 - mu) * rs * g[c1] + bta[c1];
    unsigned short h0, l0, h1, l1; split2(y0, h0, l0); split2(y1, h1, l1);
    HbfOut[gro + c0] = h0; HbfOut[hbPl + gro + c0] = l0;
    HbfOut[gro + c1] = h1; HbfOut[hbPl + gro + c1] = l1;
    Hh[(size_t)(row0g + row) * 64 + lane] = f2h(y0);
    if (MM == 2) { Hst[gro + c0] = y0; Hst[gro + c1] = y1; }
    if (MM == 0) { yb[row * 132 + c0] = y0; yb[row * 132 + c1] = y1; }
  }
  if (MM != 0) return;
  __syncthreads();   // yb now holds post-LN2 y
  // ---- qv projection for next layer (A = y from yb, B = QW frags) ----
  bf16x8 yfh[4], yfl[4];
  #pragma unroll
  for (int kf = 0; kf < 4; ++kf)
    #pragma unroll
    for (int e = 0; e < 8; ++e) {
      float v = yb[lr * 132 + kf * 32 + lg * 8 + e];
      unsigned short hi, lo; split2(v, hi, lo);
      yfh[kf][e] = (short)hi; yfl[kf][e] = (short)lo;
    }
  // 2-deep QW prefetch over 8 n-tiles per wave
  bf16x8 qwh[4], qwl[4], xwh[4], xwl[4];
  #pragma unroll
  for (int kf = 0; kf < 4; ++kf) {
    size_t bo = ((size_t)kf * 32 + wid * 8) * 512 + lane * 8;
    qwh[kf] = *reinterpret_cast<const bf16x8*>(QW + bo);
    qwl[kf] = *reinterpret_cast<const bf16x8*>(QW + qwPl + bo);
  }
  #pragma unroll
  for (int j = 0; j < 8; ++j) {
    int ntile = wid * 8 + j;
    if (j < 7) {
      #pragma unroll
      for (int kf = 0; kf < 4; ++kf) {
        size_t bo = ((size_t)kf * 32 + ntile + 1) * 512 + lane * 8;
        xwh[kf] = *reinterpret_cast<const bf16x8*>(QW + bo);
        xwl[kf] = *reinterpret_cast<const bf16x8*>(QW + qwPl + bo);
      }
    }
    f32x4 acc = {};
    #pragma unroll
    for (int kf = 0; kf < 4; ++kf) {
      acc = __builtin_amdgcn_mfma_f32_16x16x32_bf16(yfh[kf], qwh[kf], acc, 0, 0, 0);
      acc = __builtin_amdgcn_mfma_f32_16x16x32_bf16(yfl[kf], qwh[kf], acc, 0, 0, 0);
      acc = __builtin_amdgcn_mfma_f32_16x16x32_bf16(yfh[kf], qwl[kf], acc, 0, 0, 0);
    }
    int c = ntile * 16 + lr;
    #pragma unroll
    for (int r = 0; r < 4; ++r)
      st[(lg * 4 + r) * 512 + c] = f2h(acc[r]);
    if (j < 7) {
      #pragma unroll
      for (int kf = 0; kf < 4; ++kf) { qwh[kf] = xwh[kf]; qwl[kf] = xwl[kf]; }
    }
  }
  __syncthreads();
  // ---- frag-ordered writes (single tb per block) ----
  int b = row0g >> 10, t0 = row0g & 1023;
  int tb = t0 >> 4, jc = t0 >> 5, tbpar = tb & 1;
  {  // q half: 8 blocks (h, kcl); thread writes 2 consecutive u16
    int u2 = tid * 2;
    int lane2 = u2 >> 3, e0 = u2 & 7;
    #pragma unroll
    for (int fb = 0; fb < 8; ++fb) {
      int hh = fb >> 1, kcl = fb & 1;
      size_t bh = (size_t)b * NHEAD + hh;
      int t_l = lane2 & 15;
      int c_l = hh * 64 + kcl * 32 + ((lane2 >> 4) << 3) + e0;
      size_t dst = ((bh * 64 + tb) * 2 + kcl) * 512 + lane2 * 8 + e0;
      qOut[dst] = st[t_l * 512 + c_l];
      qOut[dst + 1] = st[t_l * 512 + c_l + 1];
    }
  }
  {  // v half: 16 half-blocks (h, db); 2 per pass, packed u32 writes
    int sel = tid >> 7;              // which of 2 vb this pass
    int idx2 = tid & 127;
    int wl = idx2 * 2;               // [0,256) u16 within our half
    int ll = wl >> 3, ev = wl & 7;
    int t_l = ((ll >> 4) << 3) + ev; // local t (ev, ev+1 -> t_l, t_l+1)
    int d_l = ll & 15;
    #pragma unroll
    for (int p = 0; p < 8; ++p) {
      int vb = p * 2 + sel;
      int hh = vb >> 2, db = vb & 3;
      size_t bh = (size_t)b * NHEAD + hh;
      int n = 256 + hh * 64 + db * 16 + d_l;
      unsigned int pack = (unsigned)st[t_l * 512 + n] |
                          ((unsigned)st[(t_l + 1) * 512 + n] << 16);
      size_t dstu16 = ((bh * 4 + db) * 32 + jc) * 512 + tbpar * 256 + wl;
      *reinterpret_cast<unsigned int*>(vOut + dstu16) = pack;
    }
  }
}

// ---------------- readout ----------------
__global__ __launch_bounds__(64) void k_readout(const float* __restrict__ H,
                                                const float* __restrict__ W, const float* __restrict__ b0,
                                                float* __restrict__ out) {
  int idx = blockIdx.x;           // b*512 + p
  int b = idx >> 9, p = idx & 511;
  size_t row = ((size_t)b * SEQ + 2 * p) * EMB;
  int lane = threadIdx.x;
  float acc = H[row + lane] * W[lane] + H[row + 64 + lane] * W[64 + lane];
  #pragma unroll
  for (int off = 1; off < 64; off <<= 1) acc += __shfl_xor(acc, off);
  if (lane == 0) out[idx] = acc + b0[0];
}

extern "C" void kernel_launch(void* const* d_in, const int* in_sizes, int n_in,
                              void* d_out, int out_size, void* d_ws, size_t ws_size,
                              hipStream_t stream) {
  (void)in_sizes; (void)n_in; (void)out_size; (void)ws_size;
  const float* xs        = (const float*)d_in[0];
  const float* ys        = (const float*)d_in[1];
  const float* head_mask = (const float*)d_in[2];
  const float* read_in_W = (const float*)d_in[3];
  const float* read_in_b = (const float*)d_in[4];
  const float* qW        = (const float*)d_in[5];
  const float* vW        = (const float*)d_in[6];
  const float* qW_last   = (const float*)d_in[7];
  const float* kW_last   = (const float*)d_in[8];
  const float* vW_last   = (const float*)d_in[9];
  const float* ln1_g     = (const float*)d_in[10];
  const float* ln1_b     = (const float*)d_in[11];
  const float* ln2_g     = (const float*)d_in[12];
  const float* ln2_b     = (const float*)d_in[13];
  const float* mlp_W1    = (const float*)d_in[14];
  const float* mlp_b1    = (const float*)d_in[15];
  const float* mlp_W2    = (const float*)d_in[16];
  const float* mlp_b2    = (const float*)d_in[17];
  const float* ro_W      = (const float*)d_in[18];
  const float* ro_b      = (const float*)d_in[19];

  const size_t HPL   = (size_t)BS * SEQ * EMB;          // 2M
  const size_t QVWPL = (size_t)11 * 512 * 128;
  const size_t W1PL  = (size_t)12 * 512 * 128;
  const size_t W2PL  = (size_t)12 * 512 * 128;
  const size_t LASTPL= (size_t)1536 * 128;
  const size_t VOFF  = (size_t)BS * NHEAD * 65536;      // v region inside qbuf

  char* ws = (char*)d_ws;
  size_t off = 0;
  auto alloc = [&](size_t bytes) -> void* {
    void* p = ws + off;
    off += (bytes + 255) & ~(size_t)255;
    return p;
  };
  float* H             = (float*)alloc(HPL * 4);                  // 8 MB (final layer only)
  unsigned short* Hbf  = (unsigned short*)alloc(2 * HPL * 2);     // 8 MB (state)
  unsigned short* Hbf2 = (unsigned short*)alloc(2 * HPL * 2);     // 8 MB (post-LN1)
  unsigned short* Hh   = (unsigned short*)alloc((size_t)BS * SEQ * 64 * 2);  // 2 MB
  unsigned short* qbuf = (unsigned short*)alloc((size_t)BS * NHEAD * 131072 * 2); // q | v (v7) / q-last
  unsigned short* kmid = (unsigned short*)alloc((size_t)BS * NHEAD * 131072 * 2); // k-last frag
  unsigned short* vTl  = (unsigned short*)alloc((size_t)BS * NHEAD * 131072 * 2); // last v frag
  unsigned short* qvWT = (unsigned short*)alloc(2 * QVWPL * 2);
  unsigned short* W1T  = (unsigned short*)alloc(2 * W1PL * 2);
  unsigned short* W2T  = (unsigned short*)alloc(2 * W2PL * 2);
  unsigned short* lastT= (unsigned short*)alloc(2 * LASTPL * 2);

  { int tot = 11 * 512 * 128; k_prep_qvfrag<<<dim3((tot + 255) / 256), 256, 0, stream>>>(qW, vW, qvWT, QVWPL); }
  { int tot = 12 * 512 * 128; k_prep_fragT<<<dim3((tot + 255) / 256), 256, 0, stream>>>(mlp_W1, W1T, W1PL, 12, 128, 512, 512, 128); }
  { int tot = 12 * 512 * 128; k_prep_fragT<<<dim3((tot + 255) / 256), 256, 0, stream>>>(mlp_W2, W2T, W2PL, 12, 512, 128, 128, 512); }
  { int tot = 1536 * 128; k_prep_lastfrag<<<dim3((tot + 255) / 256), 256, 0, stream>>>(qW_last, kW_last, vW_last, lastT, LASTPL); }

  k_combine_readin<<<dim3(BS * SEQ), 128, 0, stream>>>(xs, ys, read_in_W, read_in_b, Hbf, HPL, Hh);

  const int GEMM_LDS = 2 * 64 * 136 * 2;     // 34816 B
  const int MLPF_LDS = (4096 + 16384) * 2;   // 40960 B -> 4 blocks/CU

  // layer-0 qv projection (A = Hbf)
  k_gemm<3, false><<<dim3(256, 8), 256, GEMM_LDS, stream>>>(
      Hbf, HPL, qvWT, QVWPL, nullptr, 512, qbuf, qbuf + VOFF, nullptr);

  for (int l = 0; l < 11; ++l) {
    k_attn_v7<<<dim3(256), 512, 65536, stream>>>(
        qbuf, Hh, qbuf + VOFF, head_mask, Hbf, Hbf2, HPL, ln1_g + l * 128, ln1_b + l * 128);
    if (l < 10)
      k_mlpf<0><<<dim3(1024), 256, MLPF_LDS, stream>>>(
          Hbf2, HPL, W1T + (size_t)l * 65536, W1PL, mlp_b1 + l * 512,
          W2T + (size_t)l * 65536, W2PL, mlp_b2 + l * 128,
          Hbf, HPL, Hh, nullptr, ln2_g + l * 128, ln2_b + l * 128,
          qvWT + (size_t)(l + 1) * 65536, QVWPL, qbuf, qbuf + VOFF);
    else
      k_mlpf<1><<<dim3(1024), 256, MLPF_LDS, stream>>>(
          Hbf2, HPL, W1T + (size_t)l * 65536, W1PL, mlp_b1 + l * 512,
          W2T + (size_t)l * 65536, W2PL, mlp_b2 + l * 128,
          Hbf, HPL, Hh, nullptr, ln2_g + l * 128, ln2_b + l * 128,
          nullptr, 0, nullptr, nullptr);
  }
  // last layer
  k_gemm<2, false><<<dim3(256, 24), 256, GEMM_LDS, stream>>>(
      Hbf, HPL, lastT, LASTPL, nullptr, 1536, qbuf, kmid, vTl);
  k_attn_fused<<<dim3(256), 512, 65536, stream>>>(
      qbuf, kmid, vTl, head_mask, Hbf, Hbf2, HPL, ln1_g + 11 * 128, ln1_b + 11 * 128);
  k_mlpf<2><<<dim3(1024), 256, MLPF_LDS, stream>>>(
      Hbf2, HPL, W1T + (size_t)11 * 65536, W1PL, mlp_b1 + 11 * 512,
      W2T + (size_t)11 * 65536, W2PL, mlp_b2 + 11 * 128,
      Hbf, HPL, Hh, H, ln2_g + 11 * 128, ln2_b + 11 * 128,
      nullptr, 0, nullptr, nullptr);

  k_readout<<<dim3(8192), 64, 0, stream>>>(H, ro_W, ro_b, (float*)d_out);
}

// Round 16
// 917.241 us; speedup vs baseline: 1.1716x; 1.1716x over previous
//
#include <hip/hip_runtime.h>

#define BS 16
#define SEQ 1024
#define EMB 128
#define NHEAD 4
#define LN_EPS 1e-5f

typedef __attribute__((ext_vector_type(8))) short bf16x8;
typedef __attribute__((ext_vector_type(8))) _Float16 f16x8;
typedef __attribute__((ext_vector_type(4))) float f32x4;
typedef __attribute__((ext_vector_type(4))) unsigned short u16x4;
typedef __attribute__((ext_vector_type(4))) unsigned int u32x4;

__device__ __forceinline__ unsigned short f2b(float f) {
  union { float f; unsigned u; } v; v.f = f;
  unsigned r = v.u + 0x7fff + ((v.u >> 16) & 1);
  return (unsigned short)(r >> 16);
}
__device__ __forceinline__ float b2f(unsigned short u) {
  return __uint_as_float((unsigned)u << 16);
}
__device__ __forceinline__ unsigned short f2h(float f) {
  union { _Float16 h; unsigned short u; } v; v.h = (_Float16)f; return v.u;
}
// split x into hi+lo bf16 (3-term Markidis precision: rel err ~2^-17)
__device__ __forceinline__ void split2(float x, unsigned short& hi, unsigned short& lo) {
  unsigned short h = f2b(x);
  float hf = __uint_as_float((unsigned)h << 16);
  hi = h; lo = f2b(x - hf);
}
__device__ __forceinline__ float rsqrt_acc(float v) {
  float r = rsqrtf(v);
  return r * (1.5f - 0.5f * v * r * r);   // one Newton step -> ~f32-exact
}

// ---------------- weight prep: fragment-ordered 2-plane bf16 ----------------
__global__ void k_prep_fragT(const float* __restrict__ in, unsigned short* __restrict__ out,
                             size_t PL, int L, int Kin, int Nin, int N, int K) {
  int idx = blockIdx.x * 256 + threadIdx.x;
  int nblk = (N >> 4) * (K >> 5);
  int total = L * N * K;
  if (idx >= total) return;
  int e = idx & 7;
  int lane = (idx >> 3) & 63;
  int blk = (idx >> 9) % nblk;
  int l = idx / (512 * nblk);
  int nb = blk % (N >> 4), kc = blk / (N >> 4);
  int n = nb * 16 + (lane & 15);
  int k = kc * 32 + (lane >> 4) * 8 + e;
  float v = (k < Kin && n < Nin) ? in[(size_t)l * Kin * Nin + (size_t)k * Nin + n] : 0.f;
  unsigned short hi, lo; split2(v, hi, lo);
  out[idx] = hi; out[PL + idx] = lo;
}

// qvW frag: N=512, K=128; n<256 q side (h=n>>6,d=n&63, d63 zero), else v side
__global__ void k_prep_qvfrag(const float* __restrict__ qW, const float* __restrict__ vW,
                              unsigned short* __restrict__ out, size_t PL) {
  int idx = blockIdx.x * 256 + threadIdx.x;
  int total = 11 * 512 * 128;
  if (idx >= total) return;
  int e = idx & 7;
  int lane = (idx >> 3) & 63;
  int blk = (idx >> 9) & 127;       // kc*32 + nb
  int l = idx >> 16;
  int nb = blk & 31, kc = blk >> 5;
  int n = nb * 16 + (lane & 15);
  int k = kc * 32 + (lane >> 4) * 8 + e;
  float v = 0.f;
  if (n < 256) {
    int hh = n >> 6, d = n & 63;
    if (d < 63 && k >= 64 && k < 127) v = qW[(size_t)l * 63 * 252 + (size_t)(k - 64) * 252 + hh * 63 + d];
  } else {
    int n2 = n - 256, hh = n2 >> 6, d = n2 & 63;
    if (d < 63 && k < 63) v = vW[(size_t)l * 63 * 252 + (size_t)k * 252 + hh * 63 + d];
  }
  unsigned short hi, lo; split2(v, hi, lo);
  out[idx] = hi; out[PL + idx] = lo;
}

// last-layer qkv frag: N=1536, K=128
__global__ void k_prep_lastfrag(const float* __restrict__ qW, const float* __restrict__ kW,
                                const float* __restrict__ vW,
                                unsigned short* __restrict__ out, size_t PL) {
  int idx = blockIdx.x * 256 + threadIdx.x;
  int total = 1536 * 128;
  if (idx >= total) return;
  int e = idx & 7;
  int lane = (idx >> 3) & 63;
  int blk = idx >> 9;               // kc*96 + nb
  int nb = blk % 96, kc = blk / 96;
  int n = nb * 16 + (lane & 15);
  int k = kc * 32 + (lane >> 4) * 8 + e;
  int tsel = n >> 9, n2 = n & 511;
  const float* W = tsel == 0 ? qW : (tsel == 1 ? kW : vW);
  float v = W[(size_t)k * 512 + n2];
  unsigned short hi, lo; split2(v, hi, lo);
  out[idx] = hi; out[PL + idx] = lo;
}

// ---------------- combine + read_in (2-plane bf16 state only) ----------------
__global__ void k_combine_readin(const float* __restrict__ xs, const float* __restrict__ ys,
                                 const float* __restrict__ W, const float* __restrict__ bias,
                                 unsigned short* __restrict__ Hbf, size_t hbPl,
                                 unsigned short* __restrict__ Hh) {
  int blk = blockIdx.x;            // b*1024 + t
  int b = blk >> 10, t = blk & 1023, p = t >> 1;
  __shared__ float zs[64];
  int tid = threadIdx.x;           // 128
  if (tid < 64) {
    float v;
    if (tid < 63) v = xs[((size_t)b * 512 + p) * 63 + tid];
    else v = (t & 1) ? ys[(size_t)b * 512 + p] : 0.f;
    zs[tid] = v;
  }
  __syncthreads();
  float acc = bias[tid];
  #pragma unroll 8
  for (int d = 0; d < 64; ++d) acc += zs[d] * W[d * 128 + tid];
  size_t o = (size_t)blk * 128 + tid;
  unsigned short hi, lo; split2(acc, hi, lo);
  Hbf[o] = hi; Hbf[hbPl + o] = lo;
  if (tid < 64) Hh[(size_t)blk * 64 + tid] = f2h(acc);  // fp16 K image (dims 0..63)
}

// ---------------- split-precision MFMA GEMM: A LDS-staged, B fragment-ordered ----------------
// MODE 2: last qkv frag fp16; MODE 3: qv frag fp16
template<int MODE, bool RELU>
__global__ __launch_bounds__(256) void k_gemm(
    const unsigned short* __restrict__ A, size_t aPl,
    const unsigned short* __restrict__ BT, size_t bPl, const float* __restrict__ bias,
    int N,
    unsigned short* __restrict__ out0,
    unsigned short* __restrict__ out1,
    unsigned short* __restrict__ out2) {
  extern __shared__ unsigned short lds[];   // A 2 planes [64][136] = 34816 B; tile reuse
  int tid = threadIdx.x;
  int wid = tid >> 6, lane = tid & 63;
  int lr = lane & 15, lg = lane >> 4;
  int row0g = blockIdx.x * 64;
  int n0 = blockIdx.y * 64;
  unsigned short* Ah = lds;
  unsigned short* Al = Ah + 64 * 136;
  {
    const unsigned short* gA = A + (size_t)row0g * 128;
    const unsigned short* srcs[2] = { gA, gA + aPl };
    unsigned short* dsts[2] = { Ah, Al };
    #pragma unroll
    for (int p = 0; p < 2; ++p)
      #pragma unroll
      for (int it = 0; it < 4; ++it) {
        int e = it * 2048 + tid * 8;
        bf16x8 v = *reinterpret_cast<const bf16x8*>(srcs[p] + e);
        *reinterpret_cast<bf16x8*>(dsts[p] + (e >> 7) * 136 + (e & 127)) = v;
      }
  }
  __syncthreads();
  bf16x8 afh[4], afl[4];
  #pragma unroll
  for (int kf = 0; kf < 4; ++kf) {
    int o = (wid * 16 + lr) * 136 + kf * 32 + lg * 8;
    afh[kf] = *reinterpret_cast<const bf16x8*>(Ah + o);
    afl[kf] = *reinterpret_cast<const bf16x8*>(Al + o);
  }
  f32x4 acc[4] = {};
  int nhw = N >> 4;
  #pragma unroll
  for (int nf = 0; nf < 4; ++nf) {
    #pragma unroll
    for (int kf = 0; kf < 4; ++kf) {
      size_t bo = ((size_t)kf * nhw + (n0 >> 4) + nf) * 512 + lane * 8;
      bf16x8 bh = *reinterpret_cast<const bf16x8*>(BT + bo);
      bf16x8 bl = *reinterpret_cast<const bf16x8*>(BT + bPl + bo);
      acc[nf] = __builtin_amdgcn_mfma_f32_16x16x32_bf16(afh[kf], bh, acc[nf], 0, 0, 0);
      acc[nf] = __builtin_amdgcn_mfma_f32_16x16x32_bf16(afl[kf], bh, acc[nf], 0, 0, 0);
      acc[nf] = __builtin_amdgcn_mfma_f32_16x16x32_bf16(afh[kf], bl, acc[nf], 0, 0, 0);
    }
  }
  __syncthreads();   // done with staged A; reuse lds for the output tile
  #pragma unroll
  for (int nf = 0; nf < 4; ++nf) {
    int c = n0 + nf * 16 + lr;
    float bv = bias ? bias[c] : 0.f;
    #pragma unroll
    for (int r = 0; r < 4; ++r) {
      float v = acc[nf][r] + bv;
      if (RELU) v = fmaxf(v, 0.f);
      int rL = wid * 16 + lg * 4 + r, cL = nf * 16 + lr;
      ((unsigned short(*)[66])lds)[rL][cL] = f2h(v);
    }
  }
  __syncthreads();
  int u = tid * 2;
  int lane2 = u >> 3, e0 = u & 7;
  if (MODE == 2) {
    unsigned short (*t16)[66] = (unsigned short(*)[66])lds;
    int b = row0g >> 10, t0 = row0g & 1023;
    int tsel = n0 >> 9, c2b = n0 & 511, hh = c2b >> 7, dbase = c2b & 127;
    size_t bh = (size_t)b * NHEAD + hh;
    if (tsel < 2) {
      unsigned short* base = tsel ? out1 : out0;
      int tb0 = t0 >> 4, kc0 = dbase >> 5;
      #pragma unroll
      for (int fb = 0; fb < 8; ++fb) {
        int tbl = fb >> 1, kcl = fb & 1;
        int t_l = tbl * 16 + (lane2 & 15);
        int c_l = kcl * 32 + ((lane2 >> 4) << 3) + e0;
        size_t dst = ((bh * 64 + tb0 + tbl) * 4 + kc0 + kcl) * 512 + lane2 * 8 + e0;
        base[dst] = t16[t_l][c_l];
        base[dst + 1] = t16[t_l][c_l + 1];
      }
    } else {
      int db0 = dbase >> 4, jc0 = t0 >> 5;
      #pragma unroll
      for (int fb = 0; fb < 8; ++fb) {
        int dbl = fb >> 1, jcl = fb & 1;
        int c_l = dbl * 16 + (lane2 & 15);
        int t_l = jcl * 32 + ((lane2 >> 4) << 3) + e0;
        size_t dst = ((bh * 8 + db0 + dbl) * 32 + jc0 + jcl) * 512 + lane2 * 8 + e0;
        out2[dst] = t16[t_l][c_l];
        out2[dst + 1] = t16[t_l + 1][c_l];
      }
    }
  } else {  // MODE 3
    unsigned short (*t16)[66] = (unsigned short(*)[66])lds;
    int b = row0g >> 10, t0 = row0g & 1023;
    if (n0 < 256) {
      size_t bh = (size_t)b * NHEAD + (n0 >> 6);
      int tb0 = t0 >> 4;
      #pragma unroll
      for (int fb = 0; fb < 8; ++fb) {
        int tbl = fb >> 1, kcl = fb & 1;
        int t_l = tbl * 16 + (lane2 & 15);
        int c_l = kcl * 32 + ((lane2 >> 4) << 3) + e0;
        size_t dst = ((bh * 64 + tb0 + tbl) * 2 + kcl) * 512 + lane2 * 8 + e0;
        out0[dst] = t16[t_l][c_l];
        out0[dst + 1] = t16[t_l][c_l + 1];
      }
    } else {
      size_t bh = (size_t)b * NHEAD + ((n0 - 256) >> 6);
      int jc0 = t0 >> 5;
      #pragma unroll
      for (int fb = 0; fb < 8; ++fb) {
        int dbl = fb >> 1, jcl = fb & 1;
        int c_l = dbl * 16 + (lane2 & 15);
        int t_l = jcl * 32 + ((lane2 >> 4) << 3) + e0;
        size_t dst = ((bh * 4 + dbl) * 32 + jc0 + jcl) * 512 + lane2 * 8 + e0;
        out1[dst] = t16[t_l][c_l];
        out1[dst + 1] = t16[t_l + 1][c_l];
      }
    }
  }
}

// ---------------- attention v7 (layers 0-10, D=64); 2-plane state in/out ----------------
__global__ __launch_bounds__(512) void k_attn_v7(
    const unsigned short* __restrict__ q,      // fp16 frag [bh][tb 64][kc 2][512]
    const unsigned short* __restrict__ Hh,     // fp16 [b][t][64]
    const unsigned short* __restrict__ vT,     // fp16 frag [bh][db 4][jc 32][512]
    const float* __restrict__ head_mask,
    const unsigned short* __restrict__ HbfIn, unsigned short* __restrict__ HbfOut, size_t hbPl,
    const float* __restrict__ g, const float* __restrict__ bta) {
  extern __shared__ char sh[];
  int bid = blockIdx.x;
  int xcd = bid & 7, u = bid >> 3;
  int b = xcd * 2 + (u >> 4);
  int pidx = u & 15;
  int tid = threadIdx.x;
  int wid = tid >> 6, lane = tid & 63;
  int h = wid & 3, grp = wid >> 2;
  int lr = lane & 15, lg = lane >> 4;
  int i0t[2] = { pidx * 32, (31 - pidx) * 32 };
  int NSS = (33 - pidx) >> 1;

  const char* gK = (const char*)(Hh + (size_t)b * SEQ * 64);
  char* KB = sh;
  unsigned short* sw = (unsigned short*)(sh + 16384 + wid * 2560);

  const unsigned short* qh = q + (size_t)(b * NHEAD + h) * 65536;
  const unsigned short* vh = vT + (size_t)(b * NHEAD + h) * 65536;

  f16x8 qf[2][2][2];
  #pragma unroll
  for (int t = 0; t < 2; ++t)
    #pragma unroll
    for (int mf = 0; mf < 2; ++mf)
      #pragma unroll
      for (int kf = 0; kf < 2; ++kf)
        qf[t][mf][kf] = *reinterpret_cast<const f16x8*>(
            qh + ((((i0t[t] >> 4) + mf) * 2 + kf) << 9) + lane * 8);
  f32x4 oacc[2][2][4] = {};

  u32x4 sreg;
  auto SLOAD = [&](int ss) {
    sreg = *reinterpret_cast<const u32x4*>(gK + (size_t)ss * 8192 + tid * 16);
  };
  auto SWRITE = [&](int buf) {
    int row = tid >> 3, colb = (tid & 7) * 16;
    *reinterpret_cast<u32x4*>(KB + buf * 8192 + row * 128 + (colb ^ ((row & 7) << 4))) = sreg;
  };

  SLOAD(0); SWRITE(0);
  __syncthreads();

  for (int ss = 0; ss < NSS; ++ss) {
    int cur = ss & 1;
    bool more = (ss + 1 < NSS);
    if (more) SLOAD(ss + 1);
    int js = ss * 64 + grp * 32;
    if (js < i0t[1] + 32) {
      f16x8 vch[4];
      #pragma unroll
      for (int nf = 0; nf < 4; ++nf)
        vch[nf] = *reinterpret_cast<const f16x8*>(vh + ((nf * 32 + (js >> 5)) << 9) + lane * 8);
      f16x8 kfr[2][2];
      #pragma unroll
      for (int nf2 = 0; nf2 < 2; ++nf2)
        #pragma unroll
        for (int kf = 0; kf < 2; ++kf) {
          int row = grp * 32 + nf2 * 16 + lr;
          int colb = kf * 64 + lg * 16;
          kfr[nf2][kf] = *reinterpret_cast<const f16x8*>(
              KB + cur * 8192 + row * 128 + (colb ^ ((row & 7) << 4)));
        }
      #pragma unroll
      for (int t = 0; t < 2; ++t) {
        if (js < i0t[t] + 32) {
          #pragma unroll
          for (int nf2 = 0; nf2 < 2; ++nf2) {
            #pragma unroll
            for (int mf = 0; mf < 2; ++mf) {
              f32x4 sacc = {};
              #pragma unroll
              for (int kf = 0; kf < 2; ++kf)
                sacc = __builtin_amdgcn_mfma_f32_16x16x32_f16(qf[t][mf][kf], kfr[nf2][kf], sacc, 0, 0, 0);
              #pragma unroll
              for (int r = 0; r < 4; ++r) {
                int i = i0t[t] + mf * 16 + lg * 4 + r;
                int j = js + nf2 * 16 + lr;
                float v = (j <= i) ? fmaxf(sacc[r], 0.f) : 0.f;
                sw[(mf * 16 + lg * 4 + r) * 40 + nf2 * 16 + lr] = f2h(v);
              }
            }
          }
          asm volatile("s_waitcnt lgkmcnt(0)" ::: "memory");
          __builtin_amdgcn_sched_barrier(0);
          #pragma unroll
          for (int mf = 0; mf < 2; ++mf) {
            f16x8 sf = *reinterpret_cast<const f16x8*>(&sw[(mf * 16 + lr) * 40 + lg * 8]);
            #pragma unroll
            for (int nf = 0; nf < 4; ++nf)
              oacc[t][mf][nf] = __builtin_amdgcn_mfma_f32_16x16x32_f16(sf, vch[nf], oacc[t][mf][nf], 0, 0, 0);
          }
        }
      }
    }
    if (more) SWRITE(cur ^ 1);
    __syncthreads();
  }

  float hm = head_mask[h];
  float hm3 = hm * hm * hm;
  float* f8 = (float*)sh;
  for (int t = 0; t < 2; ++t) {
    #pragma unroll
    for (int mf = 0; mf < 2; ++mf)
      #pragma unroll
      for (int nf = 0; nf < 4; ++nf)
        #pragma unroll
        for (int r = 0; r < 4; ++r)
          f8[wid * 2048 + (mf * 16 + lg * 4 + r) * 64 + nf * 16 + lr] = oacc[t][mf][nf][r] * hm3;
    __syncthreads();
    for (int idx = tid; idx < 8192; idx += 512) f8[idx] += f8[idx + 8192];
    __syncthreads();
    for (int idx = tid; idx < 4096; idx += 512) f8[idx] += f8[idx + 4096];
    __syncthreads();
    for (int idx = tid; idx < 2048; idx += 512) {
      int rr = idx >> 6;
      f8[idx] = (f8[idx] + f8[idx + 2048]) / (float)(i0t[t] + rr + 1);
    }
    __syncthreads();
    for (int rl = 0; rl < 4; ++rl) {
      int rr = wid * 4 + rl;
      size_t row = ((size_t)b * SEQ + i0t[t] + rr) * EMB;
      int c0 = lane, c1 = lane + 64;
      float x0 = b2f(HbfIn[row + c0]) + b2f(HbfIn[hbPl + row + c0]);
      float x1 = b2f(HbfIn[row + c1]) + b2f(HbfIn[hbPl + row + c1]) + f8[rr * 64 + lane];
      float s1 = x0 + x1, s2 = x0 * x0 + x1 * x1;
      #pragma unroll
      for (int off = 1; off < 64; off <<= 1) {
        s1 += __shfl_xor(s1, off);
        s2 += __shfl_xor(s2, off);
      }
      float mu = s1 * (1.f / 128.f);
      float var = s2 * (1.f / 128.f) - mu * mu;
      float rs = rsqrt_acc(var + LN_EPS);
      float y0 = (x0 - mu) * rs * g[c0] + bta[c0];
      float y1 = (x1 - mu) * rs * g[c1] + bta[c1];
      unsigned short h0, l0, h1, l1; split2(y0, h0, l0); split2(y1, h1, l1);
      HbfOut[row + c0] = h0; HbfOut[hbPl + row + c0] = l0;
      HbfOut[row + c1] = h1; HbfOut[hbPl + row + c1] = l1;
    }
    __syncthreads();
  }
}

// ---------------- fused attention (+LN1), last layer (DHEAD=128); 2-plane state ----------------
__global__ __launch_bounds__(512) void k_attn_fused(
    const unsigned short* __restrict__ q,      // fp16 frag [bh][tb 64][kc 4][512]
    const unsigned short* __restrict__ kbuf,   // fp16 frag [bh][tb 64][kc 4][512]
    const unsigned short* __restrict__ vT,     // fp16 frag [bh][db 8][jc 32][512]
    const float* __restrict__ head_mask,
    const unsigned short* __restrict__ HbfIn, unsigned short* __restrict__ HbfOut, size_t hbPl,
    const float* __restrict__ g, const float* __restrict__ bta) {
  constexpr int KF = 4, NFO = 8;
  constexpr int NT = SEQ / 32;
  extern __shared__ char sh[];      // attn: sw [0,20480); epilogue f8 [0,65536)
  int bid = blockIdx.x;
  int xcd = bid & 7, u = bid >> 3;
  int b = xcd * 2 + (u >> 4);
  int pidx = u & 15;
  int tid = threadIdx.x;
  int wid = tid >> 6, lane = tid & 63;
  int h = wid & 3, grp = wid >> 2;
  int lr = lane & 15, lg = lane >> 4;
  unsigned short* sw = (unsigned short*)(sh + wid * 2560);
  const unsigned short* qh = q + (size_t)(b * NHEAD + h) * 131072;
  const unsigned short* kh = kbuf + (size_t)(b * NHEAD + h) * 131072;
  const unsigned short* vh = vT + (size_t)(b * NHEAD + h) * 131072;
  float hm = head_mask[h];
  float hm3 = hm * hm * hm;

  for (int s = 0; s < 2; ++s) {
    int tile = (s == 0) ? pidx : (NT - 1 - pidx);
    int i0 = tile * 32;
    f16x8 qf[2][KF];
    #pragma unroll
    for (int mf = 0; mf < 2; ++mf)
      #pragma unroll
      for (int kf = 0; kf < KF; ++kf)
        qf[mf][kf] = *reinterpret_cast<const f16x8*>(
            qh + ((((i0 >> 4) + mf) * 4 + kf) << 9) + lane * 8);
    f32x4 oacc[2][NFO] = {};
    int jend = i0 + 32;
    for (int j0 = grp * 32; j0 < jend; j0 += 64) {
      f16x8 vch[NFO];
      #pragma unroll
      for (int nf = 0; nf < NFO; ++nf)
        vch[nf] = *reinterpret_cast<const f16x8*>(vh + ((nf * 32 + (j0 >> 5)) << 9) + lane * 8);
      #pragma unroll
      for (int nf2 = 0; nf2 < 2; ++nf2) {
        f16x8 kfr[KF];
        #pragma unroll
        for (int kf = 0; kf < KF; ++kf)
          kfr[kf] = *reinterpret_cast<const f16x8*>(
              kh + ((((j0 >> 4) + nf2) * 4 + kf) << 9) + lane * 8);
        #pragma unroll
        for (int mf = 0; mf < 2; ++mf) {
          f32x4 sacc = {};
          #pragma unroll
          for (int kf = 0; kf < KF; ++kf)
            sacc = __builtin_amdgcn_mfma_f32_16x16x32_f16(qf[mf][kf], kfr[kf], sacc, 0, 0, 0);
          #pragma unroll
          for (int r = 0; r < 4; ++r) {
            int i = i0 + mf * 16 + lg * 4 + r;
            int j = j0 + nf2 * 16 + lr;
            float v = (j <= i) ? fmaxf(sacc[r], 0.f) : 0.f;
            sw[(mf * 16 + lg * 4 + r) * 40 + nf2 * 16 + lr] = f2h(v);
          }
        }
      }
      asm volatile("s_waitcnt lgkmcnt(0)" ::: "memory");
      __builtin_amdgcn_sched_barrier(0);
      #pragma unroll
      for (int mf = 0; mf < 2; ++mf) {
        f16x8 sf = *reinterpret_cast<const f16x8*>(&sw[(mf * 16 + lr) * 40 + lg * 8]);
        #pragma unroll
        for (int nf = 0; nf < NFO; ++nf)
          oacc[mf][nf] = __builtin_amdgcn_mfma_f32_16x16x32_f16(sf, vch[nf], oacc[mf][nf], 0, 0, 0);
      }
    }
    // ---- parallel tree head-sum: f8[4 head-regions][32][128] ----
    float* f8 = (float*)sh;
    __syncthreads();
    if (wid < 4) {
      #pragma unroll
      for (int mf = 0; mf < 2; ++mf)
        #pragma unroll
        for (int nf = 0; nf < NFO; ++nf)
          #pragma unroll
          for (int r = 0; r < 4; ++r)
            f8[(wid & 3) * 4096 + (mf * 16 + lg * 4 + r) * 128 + nf * 16 + lr] = oacc[mf][nf][r] * hm3;
    }
    __syncthreads();
    if (wid >= 4) {
      #pragma unroll
      for (int mf = 0; mf < 2; ++mf)
        #pragma unroll
        for (int nf = 0; nf < NFO; ++nf)
          #pragma unroll
          for (int r = 0; r < 4; ++r)
            f8[(wid & 3) * 4096 + (mf * 16 + lg * 4 + r) * 128 + nf * 16 + lr] += oacc[mf][nf][r] * hm3;
    }
    __syncthreads();
    for (int idx = tid; idx < 8192; idx += 512) f8[idx] += f8[idx + 8192];
    __syncthreads();
    for (int idx = tid; idx < 4096; idx += 512) {
      int rr = idx >> 7;
      f8[idx] = (f8[idx] + f8[idx + 4096]) / (float)(i0 + rr + 1);
    }
    __syncthreads();
    for (int rl = 0; rl < 4; ++rl) {
      int rr = wid * 4 + rl;
      size_t row = ((size_t)b * SEQ + i0 + rr) * EMB;
      int c0 = lane, c1 = lane + 64;
      float x0 = b2f(HbfIn[row + c0]) + b2f(HbfIn[hbPl + row + c0]) + f8[rr * 128 + c0];
      float x1 = b2f(HbfIn[row + c1]) + b2f(HbfIn[hbPl + row + c1]) + f8[rr * 128 + c1];
      float s1 = x0 + x1, s2 = x0 * x0 + x1 * x1;
      #pragma unroll
      for (int off = 1; off < 64; off <<= 1) {
        s1 += __shfl_xor(s1, off);
        s2 += __shfl_xor(s2, off);
      }
      float mu = s1 * (1.f / 128.f);
      float var = s2 * (1.f / 128.f) - mu * mu;
      float rs = rsqrt_acc(var + LN_EPS);
      float y0 = (x0 - mu) * rs * g[c0] + bta[c0];
      float y1 = (x1 - mu) * rs * g[c1] + bta[c1];
      unsigned short h0, l0, h1, l1; split2(y0, h0, l0); split2(y1, h1, l1);
      HbfOut[row + c0] = h0; HbfOut[hbPl + row + c0] = l0;
      HbfOut[row + c1] = h1; HbfOut[hbPl + row + c1] = l1;
    }
    __syncthreads();
  }
}

// ---------------- fused MLP (mlp1+mlp2+residual+LN2 [+readout on LAST]) ----------------
// 16 rows/block, grid 1024, 4 waves, LDS 40960 B (4 blocks/CU).
template<bool LAST>
__global__ __launch_bounds__(256) void k_mlpf(
    const unsigned short* __restrict__ A, size_t aPl,      // Hbf2 2-plane (post-LN1 y)
    const unsigned short* __restrict__ W1, size_t w1Pl, const float* __restrict__ b1,
    const unsigned short* __restrict__ W2, size_t w2Pl, const float* __restrict__ b2,
    unsigned short* __restrict__ HbfOut, size_t hbPl,
    unsigned short* __restrict__ Hh,
    const float* __restrict__ g, const float* __restrict__ bta,
    const float* __restrict__ roW, const float* __restrict__ roB,
    float* __restrict__ outp) {
  extern __shared__ unsigned short mlds[];
  unsigned short* As = mlds;              // 4096 u16 (2 planes x [16][128], XOR-swizzled)
  unsigned short* Mid = mlds + 4096;      // 16384 u16 (2 planes frag-ordered)
  float* yb = (float*)Mid;                // aliases Mid
  int tid = threadIdx.x;
  int wid = tid >> 6, lane = tid & 63;
  int lr = lane & 15, lg = lane >> 4;
  int row0g = blockIdx.x * 16;
  {
    const unsigned short* gA = A + (size_t)row0g * 128;
    int row = tid >> 4;
    int sc = ((tid & 15) * 8) ^ ((row & 7) << 3);
    *reinterpret_cast<bf16x8*>(As + row * 128 + sc) =
        *reinterpret_cast<const bf16x8*>(gA + tid * 8);
    *reinterpret_cast<bf16x8*>(As + 2048 + row * 128 + sc) =
        *reinterpret_cast<const bf16x8*>(gA + aPl + tid * 8);
  }
  __syncthreads();
  bf16x8 afh[4], afl[4];
  #pragma unroll
  for (int kf = 0; kf < 4; ++kf) {
    int o = lr * 128 + ((kf * 32 + lg * 8) ^ ((lr & 7) << 3));
    afh[kf] = *reinterpret_cast<const bf16x8*>(As + o);
    afl[kf] = *reinterpret_cast<const bf16x8*>(As + 2048 + o);
  }
  // ---- mlp1: wave does n-tiles wid*8..+7; 2-deep W1 prefetch ----
  bf16x8 cwh[4], cwl[4], nwh[4], nwl[4];
  #pragma unroll
  for (int kf = 0; kf < 4; ++kf) {
    size_t bo = ((size_t)kf * 32 + wid * 8) * 512 + lane * 8;
    cwh[kf] = *reinterpret_cast<const bf16x8*>(W1 + bo);
    cwl[kf] = *reinterpret_cast<const bf16x8*>(W1 + w1Pl + bo);
  }
  #pragma unroll
  for (int j = 0; j < 8; ++j) {
    int ntile = wid * 8 + j;
    if (j < 7) {
      #pragma unroll
      for (int kf = 0; kf < 4; ++kf) {
        size_t bo = ((size_t)kf * 32 + ntile + 1) * 512 + lane * 8;
        nwh[kf] = *reinterpret_cast<const bf16x8*>(W1 + bo);
        nwl[kf] = *reinterpret_cast<const bf16x8*>(W1 + w1Pl + bo);
      }
    }
    f32x4 acc = {};
    #pragma unroll
    for (int kf = 0; kf < 4; ++kf) {
      acc = __builtin_amdgcn_mfma_f32_16x16x32_bf16(afh[kf], cwh[kf], acc, 0, 0, 0);
      acc = __builtin_amdgcn_mfma_f32_16x16x32_bf16(afl[kf], cwh[kf], acc, 0, 0, 0);
      acc = __builtin_amdgcn_mfma_f32_16x16x32_bf16(afh[kf], cwl[kf], acc, 0, 0, 0);
    }
    int c = ntile * 16 + lr;
    float bv = b1[c];
    int kc = c >> 5, sub = ((c & 31) >> 3) * 128 + (c & 7);
    #pragma unroll
    for (int r = 0; r < 4; ++r) {
      float v = fmaxf(acc[r] + bv, 0.f);
      unsigned short hi, lo; split2(v, hi, lo);
      int ma = kc * 512 + sub + (lg * 4 + r) * 8;
      Mid[ma] = hi;
      Mid[8192 + ma] = lo;
    }
    if (j < 7) {
      #pragma unroll
      for (int kf = 0; kf < 4; ++kf) { cwh[kf] = nwh[kf]; cwl[kf] = nwl[kf]; }
    }
  }
  __syncthreads();
  // ---- mlp2: wave does n-tiles wid*2, wid*2+1; 2-deep W2 prefetch; Mid reads linear ----
  f32x4 acc2[2] = {};
  bf16x8 c2h[2], c2l[2], n2h[2], n2l[2];
  #pragma unroll
  for (int j = 0; j < 2; ++j) {
    size_t bo = (size_t)(wid * 2 + j) * 512 + lane * 8;
    c2h[j] = *reinterpret_cast<const bf16x8*>(W2 + bo);
    c2l[j] = *reinterpret_cast<const bf16x8*>(W2 + w2Pl + bo);
  }
  #pragma unroll
  for (int kc = 0; kc < 16; ++kc) {
    if (kc < 15) {
      #pragma unroll
      for (int j = 0; j < 2; ++j) {
        size_t bo = ((size_t)(kc + 1) * 8 + wid * 2 + j) * 512 + lane * 8;
        n2h[j] = *reinterpret_cast<const bf16x8*>(W2 + bo);
        n2l[j] = *reinterpret_cast<const bf16x8*>(W2 + w2Pl + bo);
      }
    }
    int o = kc * 512 + lane * 8;
    bf16x8 amh = *reinterpret_cast<const bf16x8*>(Mid + o);
    bf16x8 aml = *reinterpret_cast<const bf16x8*>(Mid + 8192 + o);
    #pragma unroll
    for (int j = 0; j < 2; ++j) {
      acc2[j] = __builtin_amdgcn_mfma_f32_16x16x32_bf16(amh, c2h[j], acc2[j], 0, 0, 0);
      acc2[j] = __builtin_amdgcn_mfma_f32_16x16x32_bf16(aml, c2h[j], acc2[j], 0, 0, 0);
      acc2[j] = __builtin_amdgcn_mfma_f32_16x16x32_bf16(amh, c2l[j], acc2[j], 0, 0, 0);
    }
    if (kc < 15) {
      c2h[0] = n2h[0]; c2h[1] = n2h[1];
      c2l[0] = n2l[0]; c2l[1] = n2l[1];
    }
  }
  __syncthreads();   // all waves done reading Mid (yb aliases it)
  // ---- residual (reconstructed from swizzled As) into yb ----
  #pragma unroll
  for (int j = 0; j < 2; ++j) {
    int c = (wid * 2 + j) * 16 + lr;
    float bv = b2[c];
    #pragma unroll
    for (int r = 0; r < 4; ++r) {
      int row = lg * 4 + r;
      int sc = c ^ ((row & 7) << 3);
      float yres = b2f(As[row * 128 + sc]) + b2f(As[2048 + row * 128 + sc]);
      yb[row * 132 + c] = acc2[j][r] + bv + yres;
    }
  }
  __syncthreads();
  // ---- LN2: wave owns rows wid*4 .. wid*4+3 (+fused readout on LAST) ----
  for (int rl = 0; rl < 4; ++rl) {
    int row = wid * 4 + rl;
    size_t gro = (size_t)(row0g + row) * EMB;
    int c0 = lane, c1 = lane + 64;
    float x0 = yb[row * 132 + c0];
    float x1 = yb[row * 132 + c1];
    float s1 = x0 + x1, s2 = x0 * x0 + x1 * x1;
    #pragma unroll
    for (int off = 1; off < 64; off <<= 1) {
      s1 += __shfl_xor(s1, off);
      s2 += __shfl_xor(s2, off);
    }
    float mu = s1 * (1.f / 128.f);
    float var = s2 * (1.f / 128.f) - mu * mu;
    float rs = rsqrt_acc(var + LN_EPS);
    float y0 = (x0 - mu) * rs * g[c0] + bta[c0];
    float y1 = (x1 - mu) * rs * g[c1] + bta[c1];
    unsigned short h0, l0, h1, l1; split2(y0, h0, l0); split2(y1, h1, l1);
    HbfOut[gro + c0] = h0; HbfOut[hbPl + gro + c0] = l0;
    HbfOut[gro + c1] = h1; HbfOut[hbPl + gro + c1] = l1;
    Hh[(size_t)(row0g + row) * 64 + lane] = f2h(y0);
    if (LAST) {
      int grow = row0g + row;
      if (!(grow & 1)) {   // even rows -> readout (same math as standalone kernel)
        float acc = y0 * roW[c0] + y1 * roW[c1];
        #pragma unroll
        for (int off = 1; off < 64; off <<= 1) acc += __shfl_xor(acc, off);
        if (lane == 0)
          outp[(grow >> 10) * 512 + ((grow & 1023) >> 1)] = acc + roB[0];
      }
    }
  }
}

extern "C" void kernel_launch(void* const* d_in, const int* in_sizes, int n_in,
                              void* d_out, int out_size, void* d_ws, size_t ws_size,
                              hipStream_t stream) {
  (void)in_sizes; (void)n_in; (void)out_size; (void)ws_size;
  const float* xs        = (const float*)d_in[0];
  const float* ys        = (const float*)d_in[1];
  const float* head_mask = (const float*)d_in[2];
  const float* read_in_W = (const float*)d_in[3];
  const float* read_in_b = (const float*)d_in[4];
  const float* qW        = (const float*)d_in[5];
  const float* vW        = (const float*)d_in[6];
  const float* qW_last   = (const float*)d_in[7];
  const float* kW_last   = (const float*)d_in[8];
  const float* vW_last   = (const float*)d_in[9];
  const float* ln1_g     = (const float*)d_in[10];
  const float* ln1_b     = (const float*)d_in[11];
  const float* ln2_g     = (const float*)d_in[12];
  const float* ln2_b     = (const float*)d_in[13];
  const float* mlp_W1    = (const float*)d_in[14];
  const float* mlp_b1    = (const float*)d_in[15];
  const float* mlp_W2    = (const float*)d_in[16];
  const float* mlp_b2    = (const float*)d_in[17];
  const float* ro_W      = (const float*)d_in[18];
  const float* ro_b      = (const float*)d_in[19];

  const size_t HPL   = (size_t)BS * SEQ * EMB;          // 2M
  const size_t QVWPL = (size_t)11 * 512 * 128;
  const size_t W1PL  = (size_t)12 * 512 * 128;
  const size_t W2PL  = (size_t)12 * 512 * 128;
  const size_t LASTPL= (size_t)1536 * 128;
  const size_t VOFF  = (size_t)BS * NHEAD * 65536;      // v region inside qbuf

  char* ws = (char*)d_ws;
  size_t off = 0;
  auto alloc = [&](size_t bytes) -> void* {
    void* p = ws + off;
    off += (bytes + 255) & ~(size_t)255;
    return p;
  };
  unsigned short* Hbf  = (unsigned short*)alloc(2 * HPL * 2);     // 8 MB (state)
  unsigned short* Hbf2 = (unsigned short*)alloc(2 * HPL * 2);     // 8 MB (post-LN1)
  unsigned short* Hh   = (unsigned short*)alloc((size_t)BS * SEQ * 64 * 2);  // 2 MB
  unsigned short* qbuf = (unsigned short*)alloc((size_t)BS * NHEAD * 131072 * 2); // q | v (v7) / q-last
  unsigned short* kmid = (unsigned short*)alloc((size_t)BS * NHEAD * 131072 * 2); // k-last frag
  unsigned short* vTl  = (unsigned short*)alloc((size_t)BS * NHEAD * 131072 * 2); // last v frag
  unsigned short* qvWT = (unsigned short*)alloc(2 * QVWPL * 2);
  unsigned short* W1T  = (unsigned short*)alloc(2 * W1PL * 2);
  unsigned short* W2T  = (unsigned short*)alloc(2 * W2PL * 2);
  unsigned short* lastT= (unsigned short*)alloc(2 * LASTPL * 2);

  { int tot = 11 * 512 * 128; k_prep_qvfrag<<<dim3((tot + 255) / 256), 256, 0, stream>>>(qW, vW, qvWT, QVWPL); }
  { int tot = 12 * 512 * 128; k_prep_fragT<<<dim3((tot + 255) / 256), 256, 0, stream>>>(mlp_W1, W1T, W1PL, 12, 128, 512, 512, 128); }
  { int tot = 12 * 512 * 128; k_prep_fragT<<<dim3((tot + 255) / 256), 256, 0, stream>>>(mlp_W2, W2T, W2PL, 12, 512, 128, 128, 512); }
  { int tot = 1536 * 128; k_prep_lastfrag<<<dim3((tot + 255) / 256), 256, 0, stream>>>(qW_last, kW_last, vW_last, lastT, LASTPL); }

  k_combine_readin<<<dim3(BS * SEQ), 128, 0, stream>>>(xs, ys, read_in_W, read_in_b, Hbf, HPL, Hh);

  const int GEMM_LDS = 2 * 64 * 136 * 2;     // 34816 B
  const int MLPF_LDS = (4096 + 16384) * 2;   // 40960 B -> 4 blocks/CU

  for (int l = 0; l < 11; ++l) {
    k_gemm<3, false><<<dim3(256, 8), 256, GEMM_LDS, stream>>>(
        Hbf, HPL, qvWT + (size_t)l * 65536, QVWPL, nullptr, 512,
        qbuf, qbuf + VOFF, nullptr);
    k_attn_v7<<<dim3(256), 512, 65536, stream>>>(
        qbuf, Hh, qbuf + VOFF, head_mask, Hbf, Hbf2, HPL, ln1_g + l * 128, ln1_b + l * 128);
    k_mlpf<false><<<dim3(1024), 256, MLPF_LDS, stream>>>(
        Hbf2, HPL, W1T + (size_t)l * 65536, W1PL, mlp_b1 + l * 512,
        W2T + (size_t)l * 65536, W2PL, mlp_b2 + l * 128,
        Hbf, HPL, Hh, ln2_g + l * 128, ln2_b + l * 128,
        nullptr, nullptr, nullptr);
  }
  // last layer
  k_gemm<2, false><<<dim3(256, 24), 256, GEMM_LDS, stream>>>(
      Hbf, HPL, lastT, LASTPL, nullptr, 1536, qbuf, kmid, vTl);
  k_attn_fused<<<dim3(256), 512, 65536, stream>>>(
      qbuf, kmid, vTl, head_mask, Hbf, Hbf2, HPL, ln1_g + 11 * 128, ln1_b + 11 * 128);
  k_mlpf<true><<<dim3(1024), 256, MLPF_LDS, stream>>>(
      Hbf2, HPL, W1T + (size_t)11 * 65536, W1PL, mlp_b1 + 11 * 512,
      W2T + (size_t)11 * 65536, W2PL, mlp_b2 + 11 * 128,
      Hbf, HPL, Hh, ln2_g + 11 * 128, ln2_b + 11 * 128,
      ro_W, ro_b, (float*)d_out);
}

// Round 17
// 900.186 us; speedup vs baseline: 1.1938x; 1.0189x over previous
//
#include <hip/hip_runtime.h>

#define BS 16
#define SEQ 1024
#define EMB 128
#define NHEAD 4
#define LN_EPS 1e-5f

typedef __attribute__((ext_vector_type(8))) short bf16x8;
typedef __attribute__((ext_vector_type(8))) _Float16 f16x8;
typedef __attribute__((ext_vector_type(4))) float f32x4;
typedef __attribute__((ext_vector_type(4))) unsigned short u16x4;
typedef __attribute__((ext_vector_type(4))) unsigned int u32x4;

__device__ __forceinline__ unsigned short f2b(float f) {
  union { float f; unsigned u; } v; v.f = f;
  unsigned r = v.u + 0x7fff + ((v.u >> 16) & 1);
  return (unsigned short)(r >> 16);
}
__device__ __forceinline__ float b2f(unsigned short u) {
  return __uint_as_float((unsigned)u << 16);
}
__device__ __forceinline__ unsigned short f2h(float f) {
  union { _Float16 h; unsigned short u; } v; v.h = (_Float16)f; return v.u;
}
__device__ __forceinline__ float h2ff(unsigned short u) {
  union { _Float16 h; unsigned short u; } v; v.u = u; return (float)v.h;
}
// split x into hi+lo bf16 (3-term Markidis precision: rel err ~2^-17)
__device__ __forceinline__ void split2(float x, unsigned short& hi, unsigned short& lo) {
  unsigned short h = f2b(x);
  float hf = __uint_as_float((unsigned)h << 16);
  hi = h; lo = f2b(x - hf);
}
__device__ __forceinline__ float rsqrt_acc(float v) {
  float r = rsqrtf(v);
  return r * (1.5f - 0.5f * v * r * r);   // one Newton step -> ~f32-exact
}

// ---------------- weight prep: fragment-ordered 2-plane (bf16 or fp16) ----------------
__global__ void k_prep_fragT(const float* __restrict__ in, unsigned short* __restrict__ out,
                             size_t PL, int L, int Kin, int Nin, int N, int K, int fph) {
  int idx = blockIdx.x * 256 + threadIdx.x;
  int nblk = (N >> 4) * (K >> 5);
  int total = L * N * K;
  if (idx >= total) return;
  int e = idx & 7;
  int lane = (idx >> 3) & 63;
  int blk = (idx >> 9) % nblk;
  int l = idx / (512 * nblk);
  int nb = blk % (N >> 4), kc = blk / (N >> 4);
  int n = nb * 16 + (lane & 15);
  int k = kc * 32 + (lane >> 4) * 8 + e;
  float v = (k < Kin && n < Nin) ? in[(size_t)l * Kin * Nin + (size_t)k * Nin + n] : 0.f;
  unsigned short hi, lo;
  if (fph) { hi = f2h(v); lo = f2h(v - h2ff(hi)); }
  else split2(v, hi, lo);
  out[idx] = hi; out[PL + idx] = lo;
}

// qvW frag: N=512, K=128; n<256 q side (h=n>>6,d=n&63, d63 zero), else v side
__global__ void k_prep_qvfrag(const float* __restrict__ qW, const float* __restrict__ vW,
                              unsigned short* __restrict__ out, size_t PL) {
  int idx = blockIdx.x * 256 + threadIdx.x;
  int total = 11 * 512 * 128;
  if (idx >= total) return;
  int e = idx & 7;
  int lane = (idx >> 3) & 63;
  int blk = (idx >> 9) & 127;       // kc*32 + nb
  int l = idx >> 16;
  int nb = blk & 31, kc = blk >> 5;
  int n = nb * 16 + (lane & 15);
  int k = kc * 32 + (lane >> 4) * 8 + e;
  float v = 0.f;
  if (n < 256) {
    int hh = n >> 6, d = n & 63;
    if (d < 63 && k >= 64 && k < 127) v = qW[(size_t)l * 63 * 252 + (size_t)(k - 64) * 252 + hh * 63 + d];
  } else {
    int n2 = n - 256, hh = n2 >> 6, d = n2 & 63;
    if (d < 63 && k < 63) v = vW[(size_t)l * 63 * 252 + (size_t)k * 252 + hh * 63 + d];
  }
  unsigned short hi, lo; split2(v, hi, lo);
  out[idx] = hi; out[PL + idx] = lo;
}

// last-layer qkv frag: N=1536, K=128
__global__ void k_prep_lastfrag(const float* __restrict__ qW, const float* __restrict__ kW,
                                const float* __restrict__ vW,
                                unsigned short* __restrict__ out, size_t PL) {
  int idx = blockIdx.x * 256 + threadIdx.x;
  int total = 1536 * 128;
  if (idx >= total) return;
  int e = idx & 7;
  int lane = (idx >> 3) & 63;
  int blk = idx >> 9;               // kc*96 + nb
  int nb = blk % 96, kc = blk / 96;
  int n = nb * 16 + (lane & 15);
  int k = kc * 32 + (lane >> 4) * 8 + e;
  int tsel = n >> 9, n2 = n & 511;
  const float* W = tsel == 0 ? qW : (tsel == 1 ? kW : vW);
  float v = W[(size_t)k * 512 + n2];
  unsigned short hi, lo; split2(v, hi, lo);
  out[idx] = hi; out[PL + idx] = lo;
}

// ---------------- combine + read_in (2-plane bf16 state only) ----------------
__global__ void k_combine_readin(const float* __restrict__ xs, const float* __restrict__ ys,
                                 const float* __restrict__ W, const float* __restrict__ bias,
                                 unsigned short* __restrict__ Hbf, size_t hbPl,
                                 unsigned short* __restrict__ Hh) {
  int blk = blockIdx.x;            // b*1024 + t
  int b = blk >> 10, t = blk & 1023, p = t >> 1;
  __shared__ float zs[64];
  int tid = threadIdx.x;           // 128
  if (tid < 64) {
    float v;
    if (tid < 63) v = xs[((size_t)b * 512 + p) * 63 + tid];
    else v = (t & 1) ? ys[(size_t)b * 512 + p] : 0.f;
    zs[tid] = v;
  }
  __syncthreads();
  float acc = bias[tid];
  #pragma unroll 8
  for (int d = 0; d < 64; ++d) acc += zs[d] * W[d * 128 + tid];
  size_t o = (size_t)blk * 128 + tid;
  unsigned short hi, lo; split2(acc, hi, lo);
  Hbf[o] = hi; Hbf[hbPl + o] = lo;
  if (tid < 64) Hh[(size_t)blk * 64 + tid] = f2h(acc);  // fp16 K image (dims 0..63)
}

// ---------------- split-precision MFMA GEMM: A LDS-staged, B fragment-ordered ----------------
// MODE 2: last qkv frag fp16; MODE 3: qv frag fp16
template<int MODE, bool RELU>
__global__ __launch_bounds__(256) void k_gemm(
    const unsigned short* __restrict__ A, size_t aPl,
    const unsigned short* __restrict__ BT, size_t bPl, const float* __restrict__ bias,
    int N,
    unsigned short* __restrict__ out0,
    unsigned short* __restrict__ out1,
    unsigned short* __restrict__ out2) {
  extern __shared__ unsigned short lds[];   // A 2 planes [64][136] = 34816 B; tile reuse
  int tid = threadIdx.x;
  int wid = tid >> 6, lane = tid & 63;
  int lr = lane & 15, lg = lane >> 4;
  int row0g = blockIdx.x * 64;
  int n0 = blockIdx.y * 64;
  unsigned short* Ah = lds;
  unsigned short* Al = Ah + 64 * 136;
  {
    const unsigned short* gA = A + (size_t)row0g * 128;
    const unsigned short* srcs[2] = { gA, gA + aPl };
    unsigned short* dsts[2] = { Ah, Al };
    #pragma unroll
    for (int p = 0; p < 2; ++p)
      #pragma unroll
      for (int it = 0; it < 4; ++it) {
        int e = it * 2048 + tid * 8;
        bf16x8 v = *reinterpret_cast<const bf16x8*>(srcs[p] + e);
        *reinterpret_cast<bf16x8*>(dsts[p] + (e >> 7) * 136 + (e & 127)) = v;
      }
  }
  __syncthreads();
  bf16x8 afh[4], afl[4];
  #pragma unroll
  for (int kf = 0; kf < 4; ++kf) {
    int o = (wid * 16 + lr) * 136 + kf * 32 + lg * 8;
    afh[kf] = *reinterpret_cast<const bf16x8*>(Ah + o);
    afl[kf] = *reinterpret_cast<const bf16x8*>(Al + o);
  }
  f32x4 acc[4] = {};
  int nhw = N >> 4;
  #pragma unroll
  for (int nf = 0; nf < 4; ++nf) {
    #pragma unroll
    for (int kf = 0; kf < 4; ++kf) {
      size_t bo = ((size_t)kf * nhw + (n0 >> 4) + nf) * 512 + lane * 8;
      bf16x8 bh = *reinterpret_cast<const bf16x8*>(BT + bo);
      bf16x8 bl = *reinterpret_cast<const bf16x8*>(BT + bPl + bo);
      acc[nf] = __builtin_amdgcn_mfma_f32_16x16x32_bf16(afh[kf], bh, acc[nf], 0, 0, 0);
      acc[nf] = __builtin_amdgcn_mfma_f32_16x16x32_bf16(afl[kf], bh, acc[nf], 0, 0, 0);
      acc[nf] = __builtin_amdgcn_mfma_f32_16x16x32_bf16(afh[kf], bl, acc[nf], 0, 0, 0);
    }
  }
  __syncthreads();   // done with staged A; reuse lds for the output tile
  #pragma unroll
  for (int nf = 0; nf < 4; ++nf) {
    int c = n0 + nf * 16 + lr;
    float bv = bias ? bias[c] : 0.f;
    #pragma unroll
    for (int r = 0; r < 4; ++r) {
      float v = acc[nf][r] + bv;
      if (RELU) v = fmaxf(v, 0.f);
      int rL = wid * 16 + lg * 4 + r, cL = nf * 16 + lr;
      ((unsigned short(*)[66])lds)[rL][cL] = f2h(v);
    }
  }
  __syncthreads();
  int u = tid * 2;
  int lane2 = u >> 3, e0 = u & 7;
  if (MODE == 2) {
    unsigned short (*t16)[66] = (unsigned short(*)[66])lds;
    int b = row0g >> 10, t0 = row0g & 1023;
    int tsel = n0 >> 9, c2b = n0 & 511, hh = c2b >> 7, dbase = c2b & 127;
    size_t bh = (size_t)b * NHEAD + hh;
    if (tsel < 2) {
      unsigned short* base = tsel ? out1 : out0;
      int tb0 = t0 >> 4, kc0 = dbase >> 5;
      #pragma unroll
      for (int fb = 0; fb < 8; ++fb) {
        int tbl = fb >> 1, kcl = fb & 1;
        int t_l = tbl * 16 + (lane2 & 15);
        int c_l = kcl * 32 + ((lane2 >> 4) << 3) + e0;
        size_t dst = ((bh * 64 + tb0 + tbl) * 4 + kc0 + kcl) * 512 + lane2 * 8 + e0;
        base[dst] = t16[t_l][c_l];
        base[dst + 1] = t16[t_l][c_l + 1];
      }
    } else {
      int db0 = dbase >> 4, jc0 = t0 >> 5;
      #pragma unroll
      for (int fb = 0; fb < 8; ++fb) {
        int dbl = fb >> 1, jcl = fb & 1;
        int c_l = dbl * 16 + (lane2 & 15);
        int t_l = jcl * 32 + ((lane2 >> 4) << 3) + e0;
        size_t dst = ((bh * 8 + db0 + dbl) * 32 + jc0 + jcl) * 512 + lane2 * 8 + e0;
        out2[dst] = t16[t_l][c_l];
        out2[dst + 1] = t16[t_l + 1][c_l];
      }
    }
  } else {  // MODE 3
    unsigned short (*t16)[66] = (unsigned short(*)[66])lds;
    int b = row0g >> 10, t0 = row0g & 1023;
    if (n0 < 256) {
      size_t bh = (size_t)b * NHEAD + (n0 >> 6);
      int tb0 = t0 >> 4;
      #pragma unroll
      for (int fb = 0; fb < 8; ++fb) {
        int tbl = fb >> 1, kcl = fb & 1;
        int t_l = tbl * 16 + (lane2 & 15);
        int c_l = kcl * 32 + ((lane2 >> 4) << 3) + e0;
        size_t dst = ((bh * 64 + tb0 + tbl) * 2 + kcl) * 512 + lane2 * 8 + e0;
        out0[dst] = t16[t_l][c_l];
        out0[dst + 1] = t16[t_l][c_l + 1];
      }
    } else {
      size_t bh = (size_t)b * NHEAD + ((n0 - 256) >> 6);
      int jc0 = t0 >> 5;
      #pragma unroll
      for (int fb = 0; fb < 8; ++fb) {
        int dbl = fb >> 1, jcl = fb & 1;
        int c_l = dbl * 16 + (lane2 & 15);
        int t_l = jcl * 32 + ((lane2 >> 4) << 3) + e0;
        size_t dst = ((bh * 4 + dbl) * 32 + jc0 + jcl) * 512 + lane2 * 8 + e0;
        out1[dst] = t16[t_l][c_l];
        out1[dst + 1] = t16[t_l + 1][c_l];
      }
    }
  }
}

// ---------------- attention v7 (layers 0-10, D=64); writes fp16 single-plane Hy ----------------
__global__ __launch_bounds__(512) void k_attn_v7(
    const unsigned short* __restrict__ q,      // fp16 frag [bh][tb 64][kc 2][512]
    const unsigned short* __restrict__ Hh,     // fp16 [b][t][64]
    const unsigned short* __restrict__ vT,     // fp16 frag [bh][db 4][jc 32][512]
    const float* __restrict__ head_mask,
    const unsigned short* __restrict__ HbfIn, size_t hbPl,
    unsigned short* __restrict__ HyOut,
    const float* __restrict__ g, const float* __restrict__ bta) {
  extern __shared__ char sh[];
  int bid = blockIdx.x;
  int xcd = bid & 7, u = bid >> 3;
  int b = xcd * 2 + (u >> 4);
  int pidx = u & 15;
  int tid = threadIdx.x;
  int wid = tid >> 6, lane = tid & 63;
  int h = wid & 3, grp = wid >> 2;
  int lr = lane & 15, lg = lane >> 4;
  int i0t[2] = { pidx * 32, (31 - pidx) * 32 };
  int NSS = (33 - pidx) >> 1;

  const char* gK = (const char*)(Hh + (size_t)b * SEQ * 64);
  char* KB = sh;
  unsigned short* sw = (unsigned short*)(sh + 16384 + wid * 2560);

  const unsigned short* qh = q + (size_t)(b * NHEAD + h) * 65536;
  const unsigned short* vh = vT + (size_t)(b * NHEAD + h) * 65536;

  f16x8 qf[2][2][2];
  #pragma unroll
  for (int t = 0; t < 2; ++t)
    #pragma unroll
    for (int mf = 0; mf < 2; ++mf)
      #pragma unroll
      for (int kf = 0; kf < 2; ++kf)
        qf[t][mf][kf] = *reinterpret_cast<const f16x8*>(
            qh + ((((i0t[t] >> 4) + mf) * 2 + kf) << 9) + lane * 8);
  f32x4 oacc[2][2][4] = {};

  u32x4 sreg;
  auto SLOAD = [&](int ss) {
    sreg = *reinterpret_cast<const u32x4*>(gK + (size_t)ss * 8192 + tid * 16);
  };
  auto SWRITE = [&](int buf) {
    int row = tid >> 3, colb = (tid & 7) * 16;
    *reinterpret_cast<u32x4*>(KB + buf * 8192 + row * 128 + (colb ^ ((row & 7) << 4))) = sreg;
  };

  SLOAD(0); SWRITE(0);
  __syncthreads();

  for (int ss = 0; ss < NSS; ++ss) {
    int cur = ss & 1;
    bool more = (ss + 1 < NSS);
    if (more) SLOAD(ss + 1);
    int js = ss * 64 + grp * 32;
    if (js < i0t[1] + 32) {
      f16x8 vch[4];
      #pragma unroll
      for (int nf = 0; nf < 4; ++nf)
        vch[nf] = *reinterpret_cast<const f16x8*>(vh + ((nf * 32 + (js >> 5)) << 9) + lane * 8);
      f16x8 kfr[2][2];
      #pragma unroll
      for (int nf2 = 0; nf2 < 2; ++nf2)
        #pragma unroll
        for (int kf = 0; kf < 2; ++kf) {
          int row = grp * 32 + nf2 * 16 + lr;
          int colb = kf * 64 + lg * 16;
          kfr[nf2][kf] = *reinterpret_cast<const f16x8*>(
              KB + cur * 8192 + row * 128 + (colb ^ ((row & 7) << 4)));
        }
      #pragma unroll
      for (int t = 0; t < 2; ++t) {
        if (js < i0t[t] + 32) {
          #pragma unroll
          for (int nf2 = 0; nf2 < 2; ++nf2) {
            #pragma unroll
            for (int mf = 0; mf < 2; ++mf) {
              f32x4 sacc = {};
              #pragma unroll
              for (int kf = 0; kf < 2; ++kf)
                sacc = __builtin_amdgcn_mfma_f32_16x16x32_f16(qf[t][mf][kf], kfr[nf2][kf], sacc, 0, 0, 0);
              #pragma unroll
              for (int r = 0; r < 4; ++r) {
                int i = i0t[t] + mf * 16 + lg * 4 + r;
                int j = js + nf2 * 16 + lr;
                float v = (j <= i) ? fmaxf(sacc[r], 0.f) : 0.f;
                sw[(mf * 16 + lg * 4 + r) * 40 + nf2 * 16 + lr] = f2h(v);
              }
            }
          }
          asm volatile("s_waitcnt lgkmcnt(0)" ::: "memory");
          __builtin_amdgcn_sched_barrier(0);
          #pragma unroll
          for (int mf = 0; mf < 2; ++mf) {
            f16x8 sf = *reinterpret_cast<const f16x8*>(&sw[(mf * 16 + lr) * 40 + lg * 8]);
            #pragma unroll
            for (int nf = 0; nf < 4; ++nf)
              oacc[t][mf][nf] = __builtin_amdgcn_mfma_f32_16x16x32_f16(sf, vch[nf], oacc[t][mf][nf], 0, 0, 0);
          }
        }
      }
    }
    if (more) SWRITE(cur ^ 1);
    __syncthreads();
  }

  float hm = head_mask[h];
  float hm3 = hm * hm * hm;
  float* f8 = (float*)sh;
  for (int t = 0; t < 2; ++t) {
    #pragma unroll
    for (int mf = 0; mf < 2; ++mf)
      #pragma unroll
      for (int nf = 0; nf < 4; ++nf)
        #pragma unroll
        for (int r = 0; r < 4; ++r)
          f8[wid * 2048 + (mf * 16 + lg * 4 + r) * 64 + nf * 16 + lr] = oacc[t][mf][nf][r] * hm3;
    __syncthreads();
    for (int idx = tid; idx < 8192; idx += 512) f8[idx] += f8[idx + 8192];
    __syncthreads();
    for (int idx = tid; idx < 4096; idx += 512) f8[idx] += f8[idx + 4096];
    __syncthreads();
    for (int idx = tid; idx < 2048; idx += 512) {
      int rr = idx >> 6;
      f8[idx] = (f8[idx] + f8[idx + 2048]) / (float)(i0t[t] + rr + 1);
    }
    __syncthreads();
    for (int rl = 0; rl < 4; ++rl) {
      int rr = wid * 4 + rl;
      size_t row = ((size_t)b * SEQ + i0t[t] + rr) * EMB;
      int c0 = lane, c1 = lane + 64;
      float x0 = b2f(HbfIn[row + c0]) + b2f(HbfIn[hbPl + row + c0]);
      float x1 = b2f(HbfIn[row + c1]) + b2f(HbfIn[hbPl + row + c1]) + f8[rr * 64 + lane];
      float s1 = x0 + x1, s2 = x0 * x0 + x1 * x1;
      #pragma unroll
      for (int off = 1; off < 64; off <<= 1) {
        s1 += __shfl_xor(s1, off);
        s2 += __shfl_xor(s2, off);
      }
      float mu = s1 * (1.f / 128.f);
      float var = s2 * (1.f / 128.f) - mu * mu;
      float rs = rsqrt_acc(var + LN_EPS);
      float y0 = (x0 - mu) * rs * g[c0] + bta[c0];
      float y1 = (x1 - mu) * rs * g[c1] + bta[c1];
      HyOut[row + c0] = f2h(y0);
      HyOut[row + c1] = f2h(y1);
    }
    __syncthreads();
  }
}

// ---------------- fused attention (+LN1), last layer (DHEAD=128); writes Hy fp16 ----------------
__global__ __launch_bounds__(512) void k_attn_fused(
    const unsigned short* __restrict__ q,      // fp16 frag [bh][tb 64][kc 4][512]
    const unsigned short* __restrict__ kbuf,   // fp16 frag [bh][tb 64][kc 4][512]
    const unsigned short* __restrict__ vT,     // fp16 frag [bh][db 8][jc 32][512]
    const float* __restrict__ head_mask,
    const unsigned short* __restrict__ HbfIn, size_t hbPl,
    unsigned short* __restrict__ HyOut,
    const float* __restrict__ g, const float* __restrict__ bta) {
  constexpr int KF = 4, NFO = 8;
  constexpr int NT = SEQ / 32;
  extern __shared__ char sh[];      // attn: sw [0,20480); epilogue f8 [0,65536)
  int bid = blockIdx.x;
  int xcd = bid & 7, u = bid >> 3;
  int b = xcd * 2 + (u >> 4);
  int pidx = u & 15;
  int tid = threadIdx.x;
  int wid = tid >> 6, lane = tid & 63;
  int h = wid & 3, grp = wid >> 2;
  int lr = lane & 15, lg = lane >> 4;
  unsigned short* sw = (unsigned short*)(sh + wid * 2560);
  const unsigned short* qh = q + (size_t)(b * NHEAD + h) * 131072;
  const unsigned short* kh = kbuf + (size_t)(b * NHEAD + h) * 131072;
  const unsigned short* vh = vT + (size_t)(b * NHEAD + h) * 131072;
  float hm = head_mask[h];
  float hm3 = hm * hm * hm;

  for (int s = 0; s < 2; ++s) {
    int tile = (s == 0) ? pidx : (NT - 1 - pidx);
    int i0 = tile * 32;
    f16x8 qf[2][KF];
    #pragma unroll
    for (int mf = 0; mf < 2; ++mf)
      #pragma unroll
      for (int kf = 0; kf < KF; ++kf)
        qf[mf][kf] = *reinterpret_cast<const f16x8*>(
            qh + ((((i0 >> 4) + mf) * 4 + kf) << 9) + lane * 8);
    f32x4 oacc[2][NFO] = {};
    int jend = i0 + 32;
    for (int j0 = grp * 32; j0 < jend; j0 += 64) {
      f16x8 vch[NFO];
      #pragma unroll
      for (int nf = 0; nf < NFO; ++nf)
        vch[nf] = *reinterpret_cast<const f16x8*>(vh + ((nf * 32 + (j0 >> 5)) << 9) + lane * 8);
      #pragma unroll
      for (int nf2 = 0; nf2 < 2; ++nf2) {
        f16x8 kfr[KF];
        #pragma unroll
        for (int kf = 0; kf < KF; ++kf)
          kfr[kf] = *reinterpret_cast<const f16x8*>(
              kh + ((((j0 >> 4) + nf2) * 4 + kf) << 9) + lane * 8);
        #pragma unroll
        for (int mf = 0; mf < 2; ++mf) {
          f32x4 sacc = {};
          #pragma unroll
          for (int kf = 0; kf < KF; ++kf)
            sacc = __builtin_amdgcn_mfma_f32_16x16x32_f16(qf[mf][kf], kfr[kf], sacc, 0, 0, 0);
          #pragma unroll
          for (int r = 0; r < 4; ++r) {
            int i = i0 + mf * 16 + lg * 4 + r;
            int j = j0 + nf2 * 16 + lr;
            float v = (j <= i) ? fmaxf(sacc[r], 0.f) : 0.f;
            sw[(mf * 16 + lg * 4 + r) * 40 + nf2 * 16 + lr] = f2h(v);
          }
        }
      }
      asm volatile("s_waitcnt lgkmcnt(0)" ::: "memory");
      __builtin_amdgcn_sched_barrier(0);
      #pragma unroll
      for (int mf = 0; mf < 2; ++mf) {
        f16x8 sf = *reinterpret_cast<const f16x8*>(&sw[(mf * 16 + lr) * 40 + lg * 8]);
        #pragma unroll
        for (int nf = 0; nf < NFO; ++nf)
          oacc[mf][nf] = __builtin_amdgcn_mfma_f32_16x16x32_f16(sf, vch[nf], oacc[mf][nf], 0, 0, 0);
      }
    }
    // ---- parallel tree head-sum: f8[4 head-regions][32][128] ----
    float* f8 = (float*)sh;
    __syncthreads();
    if (wid < 4) {
      #pragma unroll
      for (int mf = 0; mf < 2; ++mf)
        #pragma unroll
        for (int nf = 0; nf < NFO; ++nf)
          #pragma unroll
          for (int r = 0; r < 4; ++r)
            f8[(wid & 3) * 4096 + (mf * 16 + lg * 4 + r) * 128 + nf * 16 + lr] = oacc[mf][nf][r] * hm3;
    }
    __syncthreads();
    if (wid >= 4) {
      #pragma unroll
      for (int mf = 0; mf < 2; ++mf)
        #pragma unroll
        for (int nf = 0; nf < NFO; ++nf)
          #pragma unroll
          for (int r = 0; r < 4; ++r)
            f8[(wid & 3) * 4096 + (mf * 16 + lg * 4 + r) * 128 + nf * 16 + lr] += oacc[mf][nf][r] * hm3;
    }
    __syncthreads();
    for (int idx = tid; idx < 8192; idx += 512) f8[idx] += f8[idx + 8192];
    __syncthreads();
    for (int idx = tid; idx < 4096; idx += 512) {
      int rr = idx >> 7;
      f8[idx] = (f8[idx] + f8[idx + 4096]) / (float)(i0 + rr + 1);
    }
    __syncthreads();
    for (int rl = 0; rl < 4; ++rl) {
      int rr = wid * 4 + rl;
      size_t row = ((size_t)b * SEQ + i0 + rr) * EMB;
      int c0 = lane, c1 = lane + 64;
      float x0 = b2f(HbfIn[row + c0]) + b2f(HbfIn[hbPl + row + c0]) + f8[rr * 128 + c0];
      float x1 = b2f(HbfIn[row + c1]) + b2f(HbfIn[hbPl + row + c1]) + f8[rr * 128 + c1];
      float s1 = x0 + x1, s2 = x0 * x0 + x1 * x1;
      #pragma unroll
      for (int off = 1; off < 64; off <<= 1) {
        s1 += __shfl_xor(s1, off);
        s2 += __shfl_xor(s2, off);
      }
      float mu = s1 * (1.f / 128.f);
      float var = s2 * (1.f / 128.f) - mu * mu;
      float rs = rsqrt_acc(var + LN_EPS);
      float y0 = (x0 - mu) * rs * g[c0] + bta[c0];
      float y1 = (x1 - mu) * rs * g[c1] + bta[c1];
      HyOut[row + c0] = f2h(y0);
      HyOut[row + c1] = f2h(y1);
    }
    __syncthreads();
  }
}

// ---------------- fused MLP (mlp1+mlp2+residual+LN2 [+readout on LAST]) ----------------
// A = Hy fp16 single-plane; W1 fp16 2-plane; Mid/W2 bf16 2-plane.
// 16 rows/block, grid 1024, 4 waves, LDS 36864 B (4 blocks/CU).
template<bool LAST>
__global__ __launch_bounds__(256) void k_mlpf(
    const unsigned short* __restrict__ A,                  // Hy fp16 (post-LN1 y)
    const unsigned short* __restrict__ W1, size_t w1Pl, const float* __restrict__ b1,
    const unsigned short* __restrict__ W2, size_t w2Pl, const float* __restrict__ b2,
    unsigned short* __restrict__ HbfOut, size_t hbPl,
    unsigned short* __restrict__ Hh,
    const float* __restrict__ g, const float* __restrict__ bta,
    const float* __restrict__ roW, const float* __restrict__ roB,
    float* __restrict__ outp) {
  extern __shared__ unsigned short mlds[];
  unsigned short* As = mlds;              // 2048 u16 (fp16 [16][128], XOR-swizzled)
  unsigned short* Mid = mlds + 2048;      // 16384 u16 (2 planes frag-ordered bf16)
  float* yb = (float*)Mid;                // aliases Mid
  int tid = threadIdx.x;
  int wid = tid >> 6, lane = tid & 63;
  int lr = lane & 15, lg = lane >> 4;
  int row0g = blockIdx.x * 16;
  {
    const unsigned short* gA = A + (size_t)row0g * 128;
    int row = tid >> 4;
    int sc = ((tid & 15) * 8) ^ ((row & 7) << 3);
    *reinterpret_cast<bf16x8*>(As + row * 128 + sc) =
        *reinterpret_cast<const bf16x8*>(gA + tid * 8);
  }
  __syncthreads();
  f16x8 af[4];
  #pragma unroll
  for (int kf = 0; kf < 4; ++kf) {
    int o = lr * 128 + ((kf * 32 + lg * 8) ^ ((lr & 7) << 3));
    af[kf] = *reinterpret_cast<const f16x8*>(As + o);
  }
  // ---- mlp1 (fp16 A x fp16 2-plane W1): wave does n-tiles wid*8..+7; 2-deep prefetch ----
  f16x8 cwh[4], cwl[4], nwh[4], nwl[4];
  #pragma unroll
  for (int kf = 0; kf < 4; ++kf) {
    size_t bo = ((size_t)kf * 32 + wid * 8) * 512 + lane * 8;
    cwh[kf] = *reinterpret_cast<const f16x8*>(W1 + bo);
    cwl[kf] = *reinterpret_cast<const f16x8*>(W1 + w1Pl + bo);
  }
  #pragma unroll
  for (int j = 0; j < 8; ++j) {
    int ntile = wid * 8 + j;
    if (j < 7) {
      #pragma unroll
      for (int kf = 0; kf < 4; ++kf) {
        size_t bo = ((size_t)kf * 32 + ntile + 1) * 512 + lane * 8;
        nwh[kf] = *reinterpret_cast<const f16x8*>(W1 + bo);
        nwl[kf] = *reinterpret_cast<const f16x8*>(W1 + w1Pl + bo);
      }
    }
    f32x4 acc = {};
    #pragma unroll
    for (int kf = 0; kf < 4; ++kf) {
      acc = __builtin_amdgcn_mfma_f32_16x16x32_f16(af[kf], cwh[kf], acc, 0, 0, 0);
      acc = __builtin_amdgcn_mfma_f32_16x16x32_f16(af[kf], cwl[kf], acc, 0, 0, 0);
    }
    int c = ntile * 16 + lr;
    float bv = b1[c];
    int kc = c >> 5, sub = ((c & 31) >> 3) * 128 + (c & 7);
    #pragma unroll
    for (int r = 0; r < 4; ++r) {
      float v = fmaxf(acc[r] + bv, 0.f);
      unsigned short hi, lo; split2(v, hi, lo);
      int ma = kc * 512 + sub + (lg * 4 + r) * 8;
      Mid[ma] = hi;
      Mid[8192 + ma] = lo;
    }
    if (j < 7) {
      #pragma unroll
      for (int kf = 0; kf < 4; ++kf) { cwh[kf] = nwh[kf]; cwl[kf] = nwl[kf]; }
    }
  }
  __syncthreads();
  // ---- mlp2 (bf16): wave does n-tiles wid*2, wid*2+1; 2-deep prefetch; Mid reads linear ----
  f32x4 acc2[2] = {};
  bf16x8 c2h[2], c2l[2], n2h[2], n2l[2];
  #pragma unroll
  for (int j = 0; j < 2; ++j) {
    size_t bo = (size_t)(wid * 2 + j) * 512 + lane * 8;
    c2h[j] = *reinterpret_cast<const bf16x8*>(W2 + bo);
    c2l[j] = *reinterpret_cast<const bf16x8*>(W2 + w2Pl + bo);
  }
  #pragma unroll
  for (int kc = 0; kc < 16; ++kc) {
    if (kc < 15) {
      #pragma unroll
      for (int j = 0; j < 2; ++j) {
        size_t bo = ((size_t)(kc + 1) * 8 + wid * 2 + j) * 512 + lane * 8;
        n2h[j] = *reinterpret_cast<const bf16x8*>(W2 + bo);
        n2l[j] = *reinterpret_cast<const bf16x8*>(W2 + w2Pl + bo);
      }
    }
    int o = kc * 512 + lane * 8;
    bf16x8 amh = *reinterpret_cast<const bf16x8*>(Mid + o);
    bf16x8 aml = *reinterpret_cast<const bf16x8*>(Mid + 8192 + o);
    #pragma unroll
    for (int j = 0; j < 2; ++j) {
      acc2[j] = __builtin_amdgcn_mfma_f32_16x16x32_bf16(amh, c2h[j], acc2[j], 0, 0, 0);
      acc2[j] = __builtin_amdgcn_mfma_f32_16x16x32_bf16(aml, c2h[j], acc2[j], 0, 0, 0);
      acc2[j] = __builtin_amdgcn_mfma_f32_16x16x32_bf16(amh, c2l[j], acc2[j], 0, 0, 0);
    }
    if (kc < 15) {
      c2h[0] = n2h[0]; c2h[1] = n2h[1];
      c2l[0] = n2l[0]; c2l[1] = n2l[1];
    }
  }
  __syncthreads();   // all waves done reading Mid (yb aliases it)
  // ---- residual (reconstructed from fp16 As) into yb ----
  #pragma unroll
  for (int j = 0; j < 2; ++j) {
    int c = (wid * 2 + j) * 16 + lr;
    float bv = b2[c];
    #pragma unroll
    for (int r = 0; r < 4; ++r) {
      int row = lg * 4 + r;
      int sc = c ^ ((row & 7) << 3);
      float yres = h2ff(As[row * 128 + sc]);
      yb[row * 132 + c] = acc2[j][r] + bv + yres;
    }
  }
  __syncthreads();
  // ---- LN2: wave owns rows wid*4 .. wid*4+3 (+fused readout on LAST) ----
  for (int rl = 0; rl < 4; ++rl) {
    int row = wid * 4 + rl;
    size_t gro = (size_t)(row0g + row) * EMB;
    int c0 = lane, c1 = lane + 64;
    float x0 = yb[row * 132 + c0];
    float x1 = yb[row * 132 + c1];
    float s1 = x0 + x1, s2 = x0 * x0 + x1 * x1;
    #pragma unroll
    for (int off = 1; off < 64; off <<= 1) {
      s1 += __shfl_xor(s1, off);
      s2 += __shfl_xor(s2, off);
    }
    float mu = s1 * (1.f / 128.f);
    float var = s2 * (1.f / 128.f) - mu * mu;
    float rs = rsqrt_acc(var + LN_EPS);
    float y0 = (x0 - mu) * rs * g[c0] + bta[c0];
    float y1 = (x1 - mu) * rs * g[c1] + bta[c1];
    unsigned short h0, l0, h1, l1; split2(y0, h0, l0); split2(y1, h1, l1);
    HbfOut[gro + c0] = h0; HbfOut[hbPl + gro + c0] = l0;
    HbfOut[gro + c1] = h1; HbfOut[hbPl + gro + c1] = l1;
    Hh[(size_t)(row0g + row) * 64 + lane] = f2h(y0);
    if (LAST) {
      int grow = row0g + row;
      if (!(grow & 1)) {   // even rows -> readout
        float acc = y0 * roW[c0] + y1 * roW[c1];
        #pragma unroll
        for (int off = 1; off < 64; off <<= 1) acc += __shfl_xor(acc, off);
        if (lane == 0)
          outp[(grow >> 10) * 512 + ((grow & 1023) >> 1)] = acc + roB[0];
      }
    }
  }
}

extern "C" void kernel_launch(void* const* d_in, const int* in_sizes, int n_in,
                              void* d_out, int out_size, void* d_ws, size_t ws_size,
                              hipStream_t stream) {
  (void)in_sizes; (void)n_in; (void)out_size; (void)ws_size;
  const float* xs        = (const float*)d_in[0];
  const float* ys        = (const float*)d_in[1];
  const float* head_mask = (const float*)d_in[2];
  const float* read_in_W = (const float*)d_in[3];
  const float* read_in_b = (const float*)d_in[4];
  const float* qW        = (const float*)d_in[5];
  const float* vW        = (const float*)d_in[6];
  const float* qW_last   = (const float*)d_in[7];
  const float* kW_last   = (const float*)d_in[8];
  const float* vW_last   = (const float*)d_in[9];
  const float* ln1_g     = (const float*)d_in[10];
  const float* ln1_b     = (const float*)d_in[11];
  const float* ln2_g     = (const float*)d_in[12];
  const float* ln2_b     = (const float*)d_in[13];
  const float* mlp_W1    = (const float*)d_in[14];
  const float* mlp_b1    = (const float*)d_in[15];
  const float* mlp_W2    = (const float*)d_in[16];
  const float* mlp_b2    = (const float*)d_in[17];
  const float* ro_W      = (const float*)d_in[18];
  const float* ro_b      = (const float*)d_in[19];

  const size_t HPL   = (size_t)BS * SEQ * EMB;          // 2M
  const size_t QVWPL = (size_t)11 * 512 * 128;
  const size_t W1PL  = (size_t)12 * 512 * 128;
  const size_t W2PL  = (size_t)12 * 512 * 128;
  const size_t LASTPL= (size_t)1536 * 128;
  const size_t VOFF  = (size_t)BS * NHEAD * 65536;      // v region inside qbuf

  char* ws = (char*)d_ws;
  size_t off = 0;
  auto alloc = [&](size_t bytes) -> void* {
    void* p = ws + off;
    off += (bytes + 255) & ~(size_t)255;
    return p;
  };
  unsigned short* Hbf  = (unsigned short*)alloc(2 * HPL * 2);     // 8 MB (state, 2-plane bf16)
  unsigned short* Hy   = (unsigned short*)alloc(HPL * 2);         // 4 MB (post-LN1, fp16)
  unsigned short* Hh   = (unsigned short*)alloc((size_t)BS * SEQ * 64 * 2);  // 2 MB
  unsigned short* qbuf = (unsigned short*)alloc((size_t)BS * NHEAD * 131072 * 2); // q | v (v7) / q-last
  unsigned short* kmid = (unsigned short*)alloc((size_t)BS * NHEAD * 131072 * 2); // k-last frag
  unsigned short* vTl  = (unsigned short*)alloc((size_t)BS * NHEAD * 131072 * 2); // last v frag
  unsigned short* qvWT = (unsigned short*)alloc(2 * QVWPL * 2);
  unsigned short* W1T  = (unsigned short*)alloc(2 * W1PL * 2);
  unsigned short* W2T  = (unsigned short*)alloc(2 * W2PL * 2);
  unsigned short* lastT= (unsigned short*)alloc(2 * LASTPL * 2);

  { int tot = 11 * 512 * 128; k_prep_qvfrag<<<dim3((tot + 255) / 256), 256, 0, stream>>>(qW, vW, qvWT, QVWPL); }
  { int tot = 12 * 512 * 128; k_prep_fragT<<<dim3((tot + 255) / 256), 256, 0, stream>>>(mlp_W1, W1T, W1PL, 12, 128, 512, 512, 128, 1); }
  { int tot = 12 * 512 * 128; k_prep_fragT<<<dim3((tot + 255) / 256), 256, 0, stream>>>(mlp_W2, W2T, W2PL, 12, 512, 128, 128, 512, 0); }
  { int tot = 1536 * 128; k_prep_lastfrag<<<dim3((tot + 255) / 256), 256, 0, stream>>>(qW_last, kW_last, vW_last, lastT, LASTPL); }

  k_combine_readin<<<dim3(BS * SEQ), 128, 0, stream>>>(xs, ys, read_in_W, read_in_b, Hbf, HPL, Hh);

  const int GEMM_LDS = 2 * 64 * 136 * 2;     // 34816 B
  const int MLPF_LDS = (2048 + 16384) * 2;   // 36864 B -> 4 blocks/CU

  for (int l = 0; l < 11; ++l) {
    k_gemm<3, false><<<dim3(256, 8), 256, GEMM_LDS, stream>>>(
        Hbf, HPL, qvWT + (size_t)l * 65536, QVWPL, nullptr, 512,
        qbuf, qbuf + VOFF, nullptr);
    k_attn_v7<<<dim3(256), 512, 65536, stream>>>(
        qbuf, Hh, qbuf + VOFF, head_mask, Hbf, HPL, Hy, ln1_g + l * 128, ln1_b + l * 128);
    k_mlpf<false><<<dim3(1024), 256, MLPF_LDS, stream>>>(
        Hy, W1T + (size_t)l * 65536, W1PL, mlp_b1 + l * 512,
        W2T + (size_t)l * 65536, W2PL, mlp_b2 + l * 128,
        Hbf, HPL, Hh, ln2_g + l * 128, ln2_b + l * 128,
        nullptr, nullptr, nullptr);
  }
  // last layer
  k_gemm<2, false><<<dim3(256, 24), 256, GEMM_LDS, stream>>>(
      Hbf, HPL, lastT, LASTPL, nullptr, 1536, qbuf, kmid, vTl);
  k_attn_fused<<<dim3(256), 512, 65536, stream>>>(
      qbuf, kmid, vTl, head_mask, Hbf, HPL, Hy, ln1_g + 11 * 128, ln1_b + 11 * 128);
  k_mlpf<true><<<dim3(1024), 256, MLPF_LDS, stream>>>(
      Hy, W1T + (size_t)11 * 65536, W1PL, mlp_b1 + 11 * 512,
      W2T + (size_t)11 * 65536, W2PL, mlp_b2 + 11 * 128,
      Hbf, HPL, Hh, ln2_g + 11 * 128, ln2_b + 11 * 128,
      ro_W, ro_b, (float*)d_out);
}

// Round 18
// 896.997 us; speedup vs baseline: 1.1981x; 1.0036x over previous
//
#include <hip/hip_runtime.h>

#define BS 16
#define SEQ 1024
#define EMB 128
#define NHEAD 4
#define LN_EPS 1e-5f

typedef __attribute__((ext_vector_type(8))) short bf16x8;
typedef __attribute__((ext_vector_type(8))) _Float16 f16x8;
typedef __attribute__((ext_vector_type(4))) float f32x4;
typedef __attribute__((ext_vector_type(4))) unsigned short u16x4;
typedef __attribute__((ext_vector_type(4))) unsigned int u32x4;

__device__ __forceinline__ unsigned short f2b(float f) {
  union { float f; unsigned u; } v; v.f = f;
  unsigned r = v.u + 0x7fff + ((v.u >> 16) & 1);
  return (unsigned short)(r >> 16);
}
__device__ __forceinline__ float b2f(unsigned short u) {
  return __uint_as_float((unsigned)u << 16);
}
__device__ __forceinline__ unsigned short f2h(float f) {
  union { _Float16 h; unsigned short u; } v; v.h = (_Float16)f; return v.u;
}
__device__ __forceinline__ float h2ff(unsigned short u) {
  union { _Float16 h; unsigned short u; } v; v.u = u; return (float)v.h;
}
// split x into hi+lo bf16 (3-term Markidis precision: rel err ~2^-17)
__device__ __forceinline__ void split2(float x, unsigned short& hi, unsigned short& lo) {
  unsigned short h = f2b(x);
  float hf = __uint_as_float((unsigned)h << 16);
  hi = h; lo = f2b(x - hf);
}
__device__ __forceinline__ float rsqrt_acc(float v) {
  float r = rsqrtf(v);
  return r * (1.5f - 0.5f * v * r * r);   // one Newton step -> ~f32-exact
}

// ---------------- weight prep: fragment-ordered 2-plane (bf16 or fp16) ----------------
__global__ void k_prep_fragT(const float* __restrict__ in, unsigned short* __restrict__ out,
                             size_t PL, int L, int Kin, int Nin, int N, int K, int fph) {
  int idx = blockIdx.x * 256 + threadIdx.x;
  int nblk = (N >> 4) * (K >> 5);
  int total = L * N * K;
  if (idx >= total) return;
  int e = idx & 7;
  int lane = (idx >> 3) & 63;
  int blk = (idx >> 9) % nblk;
  int l = idx / (512 * nblk);
  int nb = blk % (N >> 4), kc = blk / (N >> 4);
  int n = nb * 16 + (lane & 15);
  int k = kc * 32 + (lane >> 4) * 8 + e;
  float v = (k < Kin && n < Nin) ? in[(size_t)l * Kin * Nin + (size_t)k * Nin + n] : 0.f;
  unsigned short hi, lo;
  if (fph) { hi = f2h(v); lo = f2h(v - h2ff(hi)); }
  else split2(v, hi, lo);
  out[idx] = hi; out[PL + idx] = lo;
}

// qvW frag: N=512, K=128; n<256 q side (h=n>>6,d=n&63, d63 zero), else v side
__global__ void k_prep_qvfrag(const float* __restrict__ qW, const float* __restrict__ vW,
                              unsigned short* __restrict__ out, size_t PL) {
  int idx = blockIdx.x * 256 + threadIdx.x;
  int total = 11 * 512 * 128;
  if (idx >= total) return;
  int e = idx & 7;
  int lane = (idx >> 3) & 63;
  int blk = (idx >> 9) & 127;       // kc*32 + nb
  int l = idx >> 16;
  int nb = blk & 31, kc = blk >> 5;
  int n = nb * 16 + (lane & 15);
  int k = kc * 32 + (lane >> 4) * 8 + e;
  float v = 0.f;
  if (n < 256) {
    int hh = n >> 6, d = n & 63;
    if (d < 63 && k >= 64 && k < 127) v = qW[(size_t)l * 63 * 252 + (size_t)(k - 64) * 252 + hh * 63 + d];
  } else {
    int n2 = n - 256, hh = n2 >> 6, d = n2 & 63;
    if (d < 63 && k < 63) v = vW[(size_t)l * 63 * 252 + (size_t)k * 252 + hh * 63 + d];
  }
  unsigned short hi, lo; split2(v, hi, lo);
  out[idx] = hi; out[PL + idx] = lo;
}

// last-layer qkv frag: N=1536, K=128
__global__ void k_prep_lastfrag(const float* __restrict__ qW, const float* __restrict__ kW,
                                const float* __restrict__ vW,
                                unsigned short* __restrict__ out, size_t PL) {
  int idx = blockIdx.x * 256 + threadIdx.x;
  int total = 1536 * 128;
  if (idx >= total) return;
  int e = idx & 7;
  int lane = (idx >> 3) & 63;
  int blk = idx >> 9;               // kc*96 + nb
  int nb = blk % 96, kc = blk / 96;
  int n = nb * 16 + (lane & 15);
  int k = kc * 32 + (lane >> 4) * 8 + e;
  int tsel = n >> 9, n2 = n & 511;
  const float* W = tsel == 0 ? qW : (tsel == 1 ? kW : vW);
  float v = W[(size_t)k * 512 + n2];
  unsigned short hi, lo; split2(v, hi, lo);
  out[idx] = hi; out[PL + idx] = lo;
}

// ---------------- combine + read_in (2-plane bf16 state only) ----------------
__global__ void k_combine_readin(const float* __restrict__ xs, const float* __restrict__ ys,
                                 const float* __restrict__ W, const float* __restrict__ bias,
                                 unsigned short* __restrict__ Hbf, size_t hbPl,
                                 unsigned short* __restrict__ Hh) {
  int blk = blockIdx.x;            // b*1024 + t
  int b = blk >> 10, t = blk & 1023, p = t >> 1;
  __shared__ float zs[64];
  int tid = threadIdx.x;           // 128
  if (tid < 64) {
    float v;
    if (tid < 63) v = xs[((size_t)b * 512 + p) * 63 + tid];
    else v = (t & 1) ? ys[(size_t)b * 512 + p] : 0.f;
    zs[tid] = v;
  }
  __syncthreads();
  float acc = bias[tid];
  #pragma unroll 8
  for (int d = 0; d < 64; ++d) acc += zs[d] * W[d * 128 + tid];
  size_t o = (size_t)blk * 128 + tid;
  unsigned short hi, lo; split2(acc, hi, lo);
  Hbf[o] = hi; Hbf[hbPl + o] = lo;
  if (tid < 64) Hh[(size_t)blk * 64 + tid] = f2h(acc);  // fp16 K image (dims 0..63)
}

// ---------------- split-precision MFMA GEMM: A LDS-staged, B fragment-ordered ----------------
// MODE 2: last qkv frag fp16; MODE 3: qv frag fp16
template<int MODE, bool RELU>
__global__ __launch_bounds__(256) void k_gemm(
    const unsigned short* __restrict__ A, size_t aPl,
    const unsigned short* __restrict__ BT, size_t bPl, const float* __restrict__ bias,
    int N,
    unsigned short* __restrict__ out0,
    unsigned short* __restrict__ out1,
    unsigned short* __restrict__ out2) {
  extern __shared__ unsigned short lds[];   // A 2 planes [64][136] = 34816 B; tile reuse
  int tid = threadIdx.x;
  int wid = tid >> 6, lane = tid & 63;
  int lr = lane & 15, lg = lane >> 4;
  int row0g = blockIdx.x * 64;
  int n0 = blockIdx.y * 64;
  unsigned short* Ah = lds;
  unsigned short* Al = Ah + 64 * 136;
  {
    const unsigned short* gA = A + (size_t)row0g * 128;
    const unsigned short* srcs[2] = { gA, gA + aPl };
    unsigned short* dsts[2] = { Ah, Al };
    #pragma unroll
    for (int p = 0; p < 2; ++p)
      #pragma unroll
      for (int it = 0; it < 4; ++it) {
        int e = it * 2048 + tid * 8;
        bf16x8 v = *reinterpret_cast<const bf16x8*>(srcs[p] + e);
        *reinterpret_cast<bf16x8*>(dsts[p] + (e >> 7) * 136 + (e & 127)) = v;
      }
  }
  __syncthreads();
  bf16x8 afh[4], afl[4];
  #pragma unroll
  for (int kf = 0; kf < 4; ++kf) {
    int o = (wid * 16 + lr) * 136 + kf * 32 + lg * 8;
    afh[kf] = *reinterpret_cast<const bf16x8*>(Ah + o);
    afl[kf] = *reinterpret_cast<const bf16x8*>(Al + o);
  }
  f32x4 acc[4] = {};
  int nhw = N >> 4;
  #pragma unroll
  for (int nf = 0; nf < 4; ++nf) {
    #pragma unroll
    for (int kf = 0; kf < 4; ++kf) {
      size_t bo = ((size_t)kf * nhw + (n0 >> 4) + nf) * 512 + lane * 8;
      bf16x8 bh = *reinterpret_cast<const bf16x8*>(BT + bo);
      bf16x8 bl = *reinterpret_cast<const bf16x8*>(BT + bPl + bo);
      acc[nf] = __builtin_amdgcn_mfma_f32_16x16x32_bf16(afh[kf], bh, acc[nf], 0, 0, 0);
      acc[nf] = __builtin_amdgcn_mfma_f32_16x16x32_bf16(afl[kf], bh, acc[nf], 0, 0, 0);
      acc[nf] = __builtin_amdgcn_mfma_f32_16x16x32_bf16(afh[kf], bl, acc[nf], 0, 0, 0);
    }
  }
  __syncthreads();   // done with staged A; reuse lds for the output tile
  #pragma unroll
  for (int nf = 0; nf < 4; ++nf) {
    int c = n0 + nf * 16 + lr;
    float bv = bias ? bias[c] : 0.f;
    #pragma unroll
    for (int r = 0; r < 4; ++r) {
      float v = acc[nf][r] + bv;
      if (RELU) v = fmaxf(v, 0.f);
      int rL = wid * 16 + lg * 4 + r, cL = nf * 16 + lr;
      ((unsigned short(*)[66])lds)[rL][cL] = f2h(v);
    }
  }
  __syncthreads();
  int u = tid * 2;
  int lane2 = u >> 3, e0 = u & 7;
  if (MODE == 2) {
    unsigned short (*t16)[66] = (unsigned short(*)[66])lds;
    int b = row0g >> 10, t0 = row0g & 1023;
    int tsel = n0 >> 9, c2b = n0 & 511, hh = c2b >> 7, dbase = c2b & 127;
    size_t bh = (size_t)b * NHEAD + hh;
    if (tsel < 2) {
      unsigned short* base = tsel ? out1 : out0;
      int tb0 = t0 >> 4, kc0 = dbase >> 5;
      #pragma unroll
      for (int fb = 0; fb < 8; ++fb) {
        int tbl = fb >> 1, kcl = fb & 1;
        int t_l = tbl * 16 + (lane2 & 15);
        int c_l = kcl * 32 + ((lane2 >> 4) << 3) + e0;
        size_t dst = ((bh * 64 + tb0 + tbl) * 4 + kc0 + kcl) * 512 + lane2 * 8 + e0;
        base[dst] = t16[t_l][c_l];
        base[dst + 1] = t16[t_l][c_l + 1];
      }
    } else {
      int db0 = dbase >> 4, jc0 = t0 >> 5;
      #pragma unroll
      for (int fb = 0; fb < 8; ++fb) {
        int dbl = fb >> 1, jcl = fb & 1;
        int c_l = dbl * 16 + (lane2 & 15);
        int t_l = jcl * 32 + ((lane2 >> 4) << 3) + e0;
        size_t dst = ((bh * 8 + db0 + dbl) * 32 + jc0 + jcl) * 512 + lane2 * 8 + e0;
        out2[dst] = t16[t_l][c_l];
        out2[dst + 1] = t16[t_l + 1][c_l];
      }
    }
  } else {  // MODE 3
    unsigned short (*t16)[66] = (unsigned short(*)[66])lds;
    int b = row0g >> 10, t0 = row0g & 1023;
    if (n0 < 256) {
      size_t bh = (size_t)b * NHEAD + (n0 >> 6);
      int tb0 = t0 >> 4;
      #pragma unroll
      for (int fb = 0; fb < 8; ++fb) {
        int tbl = fb >> 1, kcl = fb & 1;
        int t_l = tbl * 16 + (lane2 & 15);
        int c_l = kcl * 32 + ((lane2 >> 4) << 3) + e0;
        size_t dst = ((bh * 64 + tb0 + tbl) * 2 + kcl) * 512 + lane2 * 8 + e0;
        out0[dst] = t16[t_l][c_l];
        out0[dst + 1] = t16[t_l][c_l + 1];
      }
    } else {
      size_t bh = (size_t)b * NHEAD + ((n0 - 256) >> 6);
      int jc0 = t0 >> 5;
      #pragma unroll
      for (int fb = 0; fb < 8; ++fb) {
        int dbl = fb >> 1, jcl = fb & 1;
        int c_l = dbl * 16 + (lane2 & 15);
        int t_l = jcl * 32 + ((lane2 >> 4) << 3) + e0;
        size_t dst = ((bh * 4 + dbl) * 32 + jc0 + jcl) * 512 + lane2 * 8 + e0;
        out1[dst] = t16[t_l][c_l];
        out1[dst + 1] = t16[t_l + 1][c_l];
      }
    }
  }
}

// ---------------- attention v7 (layers 0-10, D=64); 32 KB LDS (2+ blocks/CU) ----------------
// Single-buffered K stage (8 KB) + 20 KB per-wave S; epilogue 4-region tree (32 KB).
__global__ __launch_bounds__(512) void k_attn_v7(
    const unsigned short* __restrict__ q,      // fp16 frag [bh][tb 64][kc 2][512]
    const unsigned short* __restrict__ Hh,     // fp16 [b][t][64]
    const unsigned short* __restrict__ vT,     // fp16 frag [bh][db 4][jc 32][512]
    const float* __restrict__ head_mask,
    const unsigned short* __restrict__ HbfIn, size_t hbPl,
    unsigned short* __restrict__ HyOut,
    const float* __restrict__ g, const float* __restrict__ bta) {
  extern __shared__ char sh[];  // [0,8K) KB; [8K,28K) sw; epilogue f8 [0,32K)
  int bid = blockIdx.x;
  int xcd = bid & 7, u = bid >> 3;
  int b = xcd * 2 + (u >> 4);
  int pidx = u & 15;
  int tid = threadIdx.x;
  int wid = tid >> 6, lane = tid & 63;
  int h = wid & 3, grp = wid >> 2;
  int lr = lane & 15, lg = lane >> 4;
  int i0t[2] = { pidx * 32, (31 - pidx) * 32 };
  int NSS = (33 - pidx) >> 1;              // supersteps of 64 keys

  const char* gK = (const char*)(Hh + (size_t)b * SEQ * 64);
  char* KB = sh;
  unsigned short* sw = (unsigned short*)(sh + 8192 + wid * 2560);

  const unsigned short* qh = q + (size_t)(b * NHEAD + h) * 65536;
  const unsigned short* vh = vT + (size_t)(b * NHEAD + h) * 65536;

  f16x8 qf[2][2][2];
  #pragma unroll
  for (int t = 0; t < 2; ++t)
    #pragma unroll
    for (int mf = 0; mf < 2; ++mf)
      #pragma unroll
      for (int kf = 0; kf < 2; ++kf)
        qf[t][mf][kf] = *reinterpret_cast<const f16x8*>(
            qh + ((((i0t[t] >> 4) + mf) * 2 + kf) << 9) + lane * 8);
  f32x4 oacc[2][2][4] = {};

  u32x4 sreg;
  auto SLOAD = [&](int ss) {
    sreg = *reinterpret_cast<const u32x4*>(gK + (size_t)ss * 8192 + tid * 16);
  };
  auto SWRITE = [&]() {
    int row = tid >> 3, colb = (tid & 7) * 16;
    *reinterpret_cast<u32x4*>(KB + row * 128 + (colb ^ ((row & 7) << 4))) = sreg;
  };

  SLOAD(0); SWRITE();
  __syncthreads();

  for (int ss = 0; ss < NSS; ++ss) {
    bool more = (ss + 1 < NSS);
    if (more) SLOAD(ss + 1);             // issue early; lands in registers
    int js = ss * 64 + grp * 32;
    if (js < i0t[1] + 32) {              // wave-uniform
      f16x8 vch[4];
      #pragma unroll
      for (int nf = 0; nf < 4; ++nf)
        vch[nf] = *reinterpret_cast<const f16x8*>(vh + ((nf * 32 + (js >> 5)) << 9) + lane * 8);
      f16x8 kfr[2][2];
      #pragma unroll
      for (int nf2 = 0; nf2 < 2; ++nf2)
        #pragma unroll
        for (int kf = 0; kf < 2; ++kf) {
          int row = grp * 32 + nf2 * 16 + lr;
          int colb = kf * 64 + lg * 16;
          kfr[nf2][kf] = *reinterpret_cast<const f16x8*>(
              KB + row * 128 + (colb ^ ((row & 7) << 4)));
        }
      #pragma unroll
      for (int t = 0; t < 2; ++t) {
        if (js < i0t[t] + 32) {          // wave-uniform
          #pragma unroll
          for (int nf2 = 0; nf2 < 2; ++nf2) {
            #pragma unroll
            for (int mf = 0; mf < 2; ++mf) {
              f32x4 sacc = {};
              #pragma unroll
              for (int kf = 0; kf < 2; ++kf)
                sacc = __builtin_amdgcn_mfma_f32_16x16x32_f16(qf[t][mf][kf], kfr[nf2][kf], sacc, 0, 0, 0);
              #pragma unroll
              for (int r = 0; r < 4; ++r) {
                int i = i0t[t] + mf * 16 + lg * 4 + r;
                int j = js + nf2 * 16 + lr;
                float v = (j <= i) ? fmaxf(sacc[r], 0.f) : 0.f;
                sw[(mf * 16 + lg * 4 + r) * 40 + nf2 * 16 + lr] = f2h(v);
              }
            }
          }
          asm volatile("s_waitcnt lgkmcnt(0)" ::: "memory");
          __builtin_amdgcn_sched_barrier(0);
          #pragma unroll
          for (int mf = 0; mf < 2; ++mf) {
            f16x8 sf = *reinterpret_cast<const f16x8*>(&sw[(mf * 16 + lr) * 40 + lg * 8]);
            #pragma unroll
            for (int nf = 0; nf < 4; ++nf)
              oacc[t][mf][nf] = __builtin_amdgcn_mfma_f32_16x16x32_f16(sf, vch[nf], oacc[t][mf][nf], 0, 0, 0);
          }
        }
      }
    }
    __syncthreads();                     // all waves done reading KB
    if (more) SWRITE();                  // overwrite single buffer
    __syncthreads();                     // new K visible
  }

  // ---- epilogue: 4-region tree (grp1 direct-adds into grp0's region; bit-identical order) ----
  float hm = head_mask[h];
  float hm3 = hm * hm * hm;
  float* f8 = (float*)sh;                // [4 regions][32][64] f32 = 32 KB
  for (int t = 0; t < 2; ++t) {
    if (wid < 4) {
      #pragma unroll
      for (int mf = 0; mf < 2; ++mf)
        #pragma unroll
        for (int nf = 0; nf < 4; ++nf)
          #pragma unroll
          for (int r = 0; r < 4; ++r)
            f8[wid * 2048 + (mf * 16 + lg * 4 + r) * 64 + nf * 16 + lr] = oacc[t][mf][nf][r] * hm3;
    }
    __syncthreads();
    if (wid >= 4) {
      #pragma unroll
      for (int mf = 0; mf < 2; ++mf)
        #pragma unroll
        for (int nf = 0; nf < 4; ++nf)
          #pragma unroll
          for (int r = 0; r < 4; ++r)
            f8[(wid & 3) * 2048 + (mf * 16 + lg * 4 + r) * 64 + nf * 16 + lr] += oacc[t][mf][nf][r] * hm3;
    }
    __syncthreads();
    for (int idx = tid; idx < 4096; idx += 512) f8[idx] += f8[idx + 4096];
    __syncthreads();
    for (int idx = tid; idx < 2048; idx += 512) {
      int rr = idx >> 6;
      f8[idx] = (f8[idx] + f8[idx + 2048]) / (float)(i0t[t] + rr + 1);
    }
    __syncthreads();
    for (int rl = 0; rl < 4; ++rl) {
      int rr = wid * 4 + rl;
      size_t row = ((size_t)b * SEQ + i0t[t] + rr) * EMB;
      int c0 = lane, c1 = lane + 64;
      float x0 = b2f(HbfIn[row + c0]) + b2f(HbfIn[hbPl + row + c0]);
      float x1 = b2f(HbfIn[row + c1]) + b2f(HbfIn[hbPl + row + c1]) + f8[rr * 64 + lane];
      float s1 = x0 + x1, s2 = x0 * x0 + x1 * x1;
      #pragma unroll
      for (int off = 1; off < 64; off <<= 1) {
        s1 += __shfl_xor(s1, off);
        s2 += __shfl_xor(s2, off);
      }
      float mu = s1 * (1.f / 128.f);
      float var = s2 * (1.f / 128.f) - mu * mu;
      float rs = rsqrt_acc(var + LN_EPS);
      float y0 = (x0 - mu) * rs * g[c0] + bta[c0];
      float y1 = (x1 - mu) * rs * g[c1] + bta[c1];
      HyOut[row + c0] = f2h(y0);
      HyOut[row + c1] = f2h(y1);
    }
    __syncthreads();
  }
}

// ---------------- fused attention (+LN1), last layer (DHEAD=128); writes Hy fp16 ----------------
__global__ __launch_bounds__(512) void k_attn_fused(
    const unsigned short* __restrict__ q,      // fp16 frag [bh][tb 64][kc 4][512]
    const unsigned short* __restrict__ kbuf,   // fp16 frag [bh][tb 64][kc 4][512]
    const unsigned short* __restrict__ vT,     // fp16 frag [bh][db 8][jc 32][512]
    const float* __restrict__ head_mask,
    const unsigned short* __restrict__ HbfIn, size_t hbPl,
    unsigned short* __restrict__ HyOut,
    const float* __restrict__ g, const float* __restrict__ bta) {
  constexpr int KF = 4, NFO = 8;
  constexpr int NT = SEQ / 32;
  extern __shared__ char sh[];      // attn: sw [0,20480); epilogue f8 [0,65536)
  int bid = blockIdx.x;
  int xcd = bid & 7, u = bid >> 3;
  int b = xcd * 2 + (u >> 4);
  int pidx = u & 15;
  int tid = threadIdx.x;
  int wid = tid >> 6, lane = tid & 63;
  int h = wid & 3, grp = wid >> 2;
  int lr = lane & 15, lg = lane >> 4;
  unsigned short* sw = (unsigned short*)(sh + wid * 2560);
  const unsigned short* qh = q + (size_t)(b * NHEAD + h) * 131072;
  const unsigned short* kh = kbuf + (size_t)(b * NHEAD + h) * 131072;
  const unsigned short* vh = vT + (size_t)(b * NHEAD + h) * 131072;
  float hm = head_mask[h];
  float hm3 = hm * hm * hm;

  for (int s = 0; s < 2; ++s) {
    int tile = (s == 0) ? pidx : (NT - 1 - pidx);
    int i0 = tile * 32;
    f16x8 qf[2][KF];
    #pragma unroll
    for (int mf = 0; mf < 2; ++mf)
      #pragma unroll
      for (int kf = 0; kf < KF; ++kf)
        qf[mf][kf] = *reinterpret_cast<const f16x8*>(
            qh + ((((i0 >> 4) + mf) * 4 + kf) << 9) + lane * 8);
    f32x4 oacc[2][NFO] = {};
    int jend = i0 + 32;
    for (int j0 = grp * 32; j0 < jend; j0 += 64) {
      f16x8 vch[NFO];
      #pragma unroll
      for (int nf = 0; nf < NFO; ++nf)
        vch[nf] = *reinterpret_cast<const f16x8*>(vh + ((nf * 32 + (j0 >> 5)) << 9) + lane * 8);
      #pragma unroll
      for (int nf2 = 0; nf2 < 2; ++nf2) {
        f16x8 kfr[KF];
        #pragma unroll
        for (int kf = 0; kf < KF; ++kf)
          kfr[kf] = *reinterpret_cast<const f16x8*>(
              kh + ((((j0 >> 4) + nf2) * 4 + kf) << 9) + lane * 8);
        #pragma unroll
        for (int mf = 0; mf < 2; ++mf) {
          f32x4 sacc = {};
          #pragma unroll
          for (int kf = 0; kf < KF; ++kf)
            sacc = __builtin_amdgcn_mfma_f32_16x16x32_f16(qf[mf][kf], kfr[kf], sacc, 0, 0, 0);
          #pragma unroll
          for (int r = 0; r < 4; ++r) {
            int i = i0 + mf * 16 + lg * 4 + r;
            int j = j0 + nf2 * 16 + lr;
            float v = (j <= i) ? fmaxf(sacc[r], 0.f) : 0.f;
            sw[(mf * 16 + lg * 4 + r) * 40 + nf2 * 16 + lr] = f2h(v);
          }
        }
      }
      asm volatile("s_waitcnt lgkmcnt(0)" ::: "memory");
      __builtin_amdgcn_sched_barrier(0);
      #pragma unroll
      for (int mf = 0; mf < 2; ++mf) {
        f16x8 sf = *reinterpret_cast<const f16x8*>(&sw[(mf * 16 + lr) * 40 + lg * 8]);
        #pragma unroll
        for (int nf = 0; nf < NFO; ++nf)
          oacc[mf][nf] = __builtin_amdgcn_mfma_f32_16x16x32_f16(sf, vch[nf], oacc[mf][nf], 0, 0, 0);
      }
    }
    // ---- parallel tree head-sum: f8[4 head-regions][32][128] ----
    float* f8 = (float*)sh;
    __syncthreads();
    if (wid < 4) {
      #pragma unroll
      for (int mf = 0; mf < 2; ++mf)
        #pragma unroll
        for (int nf = 0; nf < NFO; ++nf)
          #pragma unroll
          for (int r = 0; r < 4; ++r)
            f8[(wid & 3) * 4096 + (mf * 16 + lg * 4 + r) * 128 + nf * 16 + lr] = oacc[mf][nf][r] * hm3;
    }
    __syncthreads();
    if (wid >= 4) {
      #pragma unroll
      for (int mf = 0; mf < 2; ++mf)
        #pragma unroll
        for (int nf = 0; nf < NFO; ++nf)
          #pragma unroll
          for (int r = 0; r < 4; ++r)
            f8[(wid & 3) * 4096 + (mf * 16 + lg * 4 + r) * 128 + nf * 16 + lr] += oacc[mf][nf][r] * hm3;
    }
    __syncthreads();
    for (int idx = tid; idx < 8192; idx += 512) f8[idx] += f8[idx + 8192];
    __syncthreads();
    for (int idx = tid; idx < 4096; idx += 512) {
      int rr = idx >> 7;
      f8[idx] = (f8[idx] + f8[idx + 4096]) / (float)(i0 + rr + 1);
    }
    __syncthreads();
    for (int rl = 0; rl < 4; ++rl) {
      int rr = wid * 4 + rl;
      size_t row = ((size_t)b * SEQ + i0 + rr) * EMB;
      int c0 = lane, c1 = lane + 64;
      float x0 = b2f(HbfIn[row + c0]) + b2f(HbfIn[hbPl + row + c0]) + f8[rr * 128 + c0];
      float x1 = b2f(HbfIn[row + c1]) + b2f(HbfIn[hbPl + row + c1]) + f8[rr * 128 + c1];
      float s1 = x0 + x1, s2 = x0 * x0 + x1 * x1;
      #pragma unroll
      for (int off = 1; off < 64; off <<= 1) {
        s1 += __shfl_xor(s1, off);
        s2 += __shfl_xor(s2, off);
      }
      float mu = s1 * (1.f / 128.f);
      float var = s2 * (1.f / 128.f) - mu * mu;
      float rs = rsqrt_acc(var + LN_EPS);
      float y0 = (x0 - mu) * rs * g[c0] + bta[c0];
      float y1 = (x1 - mu) * rs * g[c1] + bta[c1];
      HyOut[row + c0] = f2h(y0);
      HyOut[row + c1] = f2h(y1);
    }
    __syncthreads();
  }
}

// ---------------- fused MLP (mlp1+mlp2+residual+LN2 [+readout on LAST]) ----------------
// A = Hy fp16 single-plane; W1 fp16 2-plane; Mid/W2 bf16 2-plane.
// 16 rows/block, grid 1024, 4 waves, LDS 36864 B (4 blocks/CU).
template<bool LAST>
__global__ __launch_bounds__(256) void k_mlpf(
    const unsigned short* __restrict__ A,                  // Hy fp16 (post-LN1 y)
    const unsigned short* __restrict__ W1, size_t w1Pl, const float* __restrict__ b1,
    const unsigned short* __restrict__ W2, size_t w2Pl, const float* __restrict__ b2,
    unsigned short* __restrict__ HbfOut, size_t hbPl,
    unsigned short* __restrict__ Hh,
    const float* __restrict__ g, const float* __restrict__ bta,
    const float* __restrict__ roW, const float* __restrict__ roB,
    float* __restrict__ outp) {
  extern __shared__ unsigned short mlds[];
  unsigned short* As = mlds;              // 2048 u16 (fp16 [16][128], XOR-swizzled)
  unsigned short* Mid = mlds + 2048;      // 16384 u16 (2 planes frag-ordered bf16)
  float* yb = (float*)Mid;                // aliases Mid
  int tid = threadIdx.x;
  int wid = tid >> 6, lane = tid & 63;
  int lr = lane & 15, lg = lane >> 4;
  int row0g = blockIdx.x * 16;
  {
    const unsigned short* gA = A + (size_t)row0g * 128;
    int row = tid >> 4;
    int sc = ((tid & 15) * 8) ^ ((row & 7) << 3);
    *reinterpret_cast<bf16x8*>(As + row * 128 + sc) =
        *reinterpret_cast<const bf16x8*>(gA + tid * 8);
  }
  __syncthreads();
  f16x8 af[4];
  #pragma unroll
  for (int kf = 0; kf < 4; ++kf) {
    int o = lr * 128 + ((kf * 32 + lg * 8) ^ ((lr & 7) << 3));
    af[kf] = *reinterpret_cast<const f16x8*>(As + o);
  }
  // ---- mlp1 (fp16 A x fp16 2-plane W1): wave does n-tiles wid*8..+7; 2-deep prefetch ----
  f16x8 cwh[4], cwl[4], nwh[4], nwl[4];
  #pragma unroll
  for (int kf = 0; kf < 4; ++kf) {
    size_t bo = ((size_t)kf * 32 + wid * 8) * 512 + lane * 8;
    cwh[kf] = *reinterpret_cast<const f16x8*>(W1 + bo);
    cwl[kf] = *reinterpret_cast<const f16x8*>(W1 + w1Pl + bo);
  }
  #pragma unroll
  for (int j = 0; j < 8; ++j) {
    int ntile = wid * 8 + j;
    if (j < 7) {
      #pragma unroll
      for (int kf = 0; kf < 4; ++kf) {
        size_t bo = ((size_t)kf * 32 + ntile + 1) * 512 + lane * 8;
        nwh[kf] = *reinterpret_cast<const f16x8*>(W1 + bo);
        nwl[kf] = *reinterpret_cast<const f16x8*>(W1 + w1Pl + bo);
      }
    }
    f32x4 acc = {};
    #pragma unroll
    for (int kf = 0; kf < 4; ++kf) {
      acc = __builtin_amdgcn_mfma_f32_16x16x32_f16(af[kf], cwh[kf], acc, 0, 0, 0);
      acc = __builtin_amdgcn_mfma_f32_16x16x32_f16(af[kf], cwl[kf], acc, 0, 0, 0);
    }
    int c = ntile * 16 + lr;
    float bv = b1[c];
    int kc = c >> 5, sub = ((c & 31) >> 3) * 128 + (c & 7);
    #pragma unroll
    for (int r = 0; r < 4; ++r) {
      float v = fmaxf(acc[r] + bv, 0.f);
      unsigned short hi, lo; split2(v, hi, lo);
      int ma = kc * 512 + sub + (lg * 4 + r) * 8;
      Mid[ma] = hi;
      Mid[8192 + ma] = lo;
    }
    if (j < 7) {
      #pragma unroll
      for (int kf = 0; kf < 4; ++kf) { cwh[kf] = nwh[kf]; cwl[kf] = nwl[kf]; }
    }
  }
  __syncthreads();
  // ---- mlp2 (bf16): wave does n-tiles wid*2, wid*2+1; 2-deep prefetch; Mid reads linear ----
  f32x4 acc2[2] = {};
  bf16x8 c2h[2], c2l[2], n2h[2], n2l[2];
  #pragma unroll
  for (int j = 0; j < 2; ++j) {
    size_t bo = (size_t)(wid * 2 + j) * 512 + lane * 8;
    c2h[j] = *reinterpret_cast<const bf16x8*>(W2 + bo);
    c2l[j] = *reinterpret_cast<const bf16x8*>(W2 + w2Pl + bo);
  }
  #pragma unroll
  for (int kc = 0; kc < 16; ++kc) {
    if (kc < 15) {
      #pragma unroll
      for (int j = 0; j < 2; ++j) {
        size_t bo = ((size_t)(kc + 1) * 8 + wid * 2 + j) * 512 + lane * 8;
        n2h[j] = *reinterpret_cast<const bf16x8*>(W2 + bo);
        n2l[j] = *reinterpret_cast<const bf16x8*>(W2 + w2Pl + bo);
      }
    }
    int o = kc * 512 + lane * 8;
    bf16x8 amh = *reinterpret_cast<const bf16x8*>(Mid + o);
    bf16x8 aml = *reinterpret_cast<const bf16x8*>(Mid + 8192 + o);
    #pragma unroll
    for (int j = 0; j < 2; ++j) {
      acc2[j] = __builtin_amdgcn_mfma_f32_16x16x32_bf16(amh, c2h[j], acc2[j], 0, 0, 0);
      acc2[j] = __builtin_amdgcn_mfma_f32_16x16x32_bf16(aml, c2h[j], acc2[j], 0, 0, 0);
      acc2[j] = __builtin_amdgcn_mfma_f32_16x16x32_bf16(amh, c2l[j], acc2[j], 0, 0, 0);
    }
    if (kc < 15) {
      c2h[0] = n2h[0]; c2h[1] = n2h[1];
      c2l[0] = n2l[0]; c2l[1] = n2l[1];
    }
  }
  __syncthreads();   // all waves done reading Mid (yb aliases it)
  // ---- residual (reconstructed from fp16 As) into yb ----
  #pragma unroll
  for (int j = 0; j < 2; ++j) {
    int c = (wid * 2 + j) * 16 + lr;
    float bv = b2[c];
    #pragma unroll
    for (int r = 0; r < 4; ++r) {
      int row = lg * 4 + r;
      int sc = c ^ ((row & 7) << 3);
      float yres = h2ff(As[row * 128 + sc]);
      yb[row * 132 + c] = acc2[j][r] + bv + yres;
    }
  }
  __syncthreads();
  // ---- LN2: wave owns rows wid*4 .. wid*4+3 (+fused readout on LAST) ----
  for (int rl = 0; rl < 4; ++rl) {
    int row = wid * 4 + rl;
    size_t gro = (size_t)(row0g + row) * EMB;
    int c0 = lane, c1 = lane + 64;
    float x0 = yb[row * 132 + c0];
    float x1 = yb[row * 132 + c1];
    float s1 = x0 + x1, s2 = x0 * x0 + x1 * x1;
    #pragma unroll
    for (int off = 1; off < 64; off <<= 1) {
      s1 += __shfl_xor(s1, off);
      s2 += __shfl_xor(s2, off);
    }
    float mu = s1 * (1.f / 128.f);
    float var = s2 * (1.f / 128.f) - mu * mu;
    float rs = rsqrt_acc(var + LN_EPS);
    float y0 = (x0 - mu) * rs * g[c0] + bta[c0];
    float y1 = (x1 - mu) * rs * g[c1] + bta[c1];
    unsigned short h0, l0, h1, l1; split2(y0, h0, l0); split2(y1, h1, l1);
    HbfOut[gro + c0] = h0; HbfOut[hbPl + gro + c0] = l0;
    HbfOut[gro + c1] = h1; HbfOut[hbPl + gro + c1] = l1;
    Hh[(size_t)(row0g + row) * 64 + lane] = f2h(y0);
    if (LAST) {
      int grow = row0g + row;
      if (!(grow & 1)) {   // even rows -> readout
        float acc = y0 * roW[c0] + y1 * roW[c1];
        #pragma unroll
        for (int off = 1; off < 64; off <<= 1) acc += __shfl_xor(acc, off);
        if (lane == 0)
          outp[(grow >> 10) * 512 + ((grow & 1023) >> 1)] = acc + roB[0];
      }
    }
  }
}

extern "C" void kernel_launch(void* const* d_in, const int* in_sizes, int n_in,
                              void* d_out, int out_size, void* d_ws, size_t ws_size,
                              hipStream_t stream) {
  (void)in_sizes; (void)n_in; (void)out_size; (void)ws_size;
  const float* xs        = (const float*)d_in[0];
  const float* ys        = (const float*)d_in[1];
  const float* head_mask = (const float*)d_in[2];
  const float* read_in_W = (const float*)d_in[3];
  const float* read_in_b = (const float*)d_in[4];
  const float* qW        = (const float*)d_in[5];
  const float* vW        = (const float*)d_in[6];
  const float* qW_last   = (const float*)d_in[7];
  const float* kW_last   = (const float*)d_in[8];
  const float* vW_last   = (const float*)d_in[9];
  const float* ln1_g     = (const float*)d_in[10];
  const float* ln1_b     = (const float*)d_in[11];
  const float* ln2_g     = (const float*)d_in[12];
  const float* ln2_b     = (const float*)d_in[13];
  const float* mlp_W1    = (const float*)d_in[14];
  const float* mlp_b1    = (const float*)d_in[15];
  const float* mlp_W2    = (const float*)d_in[16];
  const float* mlp_b2    = (const float*)d_in[17];
  const float* ro_W      = (const float*)d_in[18];
  const float* ro_b      = (const float*)d_in[19];

  const size_t HPL   = (size_t)BS * SEQ * EMB;          // 2M
  const size_t QVWPL = (size_t)11 * 512 * 128;
  const size_t W1PL  = (size_t)12 * 512 * 128;
  const size_t W2PL  = (size_t)12 * 512 * 128;
  const size_t LASTPL= (size_t)1536 * 128;
  const size_t VOFF  = (size_t)BS * NHEAD * 65536;      // v region inside qbuf

  char* ws = (char*)d_ws;
  size_t off = 0;
  auto alloc = [&](size_t bytes) -> void* {
    void* p = ws + off;
    off += (bytes + 255) & ~(size_t)255;
    return p;
  };
  unsigned short* Hbf  = (unsigned short*)alloc(2 * HPL * 2);     // 8 MB (state, 2-plane bf16)
  unsigned short* Hy   = (unsigned short*)alloc(HPL * 2);         // 4 MB (post-LN1, fp16)
  unsigned short* Hh   = (unsigned short*)alloc((size_t)BS * SEQ * 64 * 2);  // 2 MB
  unsigned short* qbuf = (unsigned short*)alloc((size_t)BS * NHEAD * 131072 * 2); // q | v (v7) / q-last
  unsigned short* kmid = (unsigned short*)alloc((size_t)BS * NHEAD * 131072 * 2); // k-last frag
  unsigned short* vTl  = (unsigned short*)alloc((size_t)BS * NHEAD * 131072 * 2); // last v frag
  unsigned short* qvWT = (unsigned short*)alloc(2 * QVWPL * 2);
  unsigned short* W1T  = (unsigned short*)alloc(2 * W1PL * 2);
  unsigned short* W2T  = (unsigned short*)alloc(2 * W2PL * 2);
  unsigned short* lastT= (unsigned short*)alloc(2 * LASTPL * 2);

  { int tot = 11 * 512 * 128; k_prep_qvfrag<<<dim3((tot + 255) / 256), 256, 0, stream>>>(qW, vW, qvWT, QVWPL); }
  { int tot = 12 * 512 * 128; k_prep_fragT<<<dim3((tot + 255) / 256), 256, 0, stream>>>(mlp_W1, W1T, W1PL, 12, 128, 512, 512, 128, 1); }
  { int tot = 12 * 512 * 128; k_prep_fragT<<<dim3((tot + 255) / 256), 256, 0, stream>>>(mlp_W2, W2T, W2PL, 12, 512, 128, 128, 512, 0); }
  { int tot = 1536 * 128; k_prep_lastfrag<<<dim3((tot + 255) / 256), 256, 0, stream>>>(qW_last, kW_last, vW_last, lastT, LASTPL); }

  k_combine_readin<<<dim3(BS * SEQ), 128, 0, stream>>>(xs, ys, read_in_W, read_in_b, Hbf, HPL, Hh);

  const int GEMM_LDS = 2 * 64 * 136 * 2;     // 34816 B
  const int ATTN_LDS = 32768;                // 32 KB -> 2+ blocks/CU
  const int MLPF_LDS = (2048 + 16384) * 2;   // 36864 B -> 4 blocks/CU

  for (int l = 0; l < 11; ++l) {
    k_gemm<3, false><<<dim3(256, 8), 256, GEMM_LDS, stream>>>(
        Hbf, HPL, qvWT + (size_t)l * 65536, QVWPL, nullptr, 512,
        qbuf, qbuf + VOFF, nullptr);
    k_attn_v7<<<dim3(256), 512, ATTN_LDS, stream>>>(
        qbuf, Hh, qbuf + VOFF, head_mask, Hbf, HPL, Hy, ln1_g + l * 128, ln1_b + l * 128);
    k_mlpf<false><<<dim3(1024), 256, MLPF_LDS, stream>>>(
        Hy, W1T + (size_t)l * 65536, W1PL, mlp_b1 + l * 512,
        W2T + (size_t)l * 65536, W2PL, mlp_b2 + l * 128,
        Hbf, HPL, Hh, ln2_g + l * 128, ln2_b + l * 128,
        nullptr, nullptr, nullptr);
  }
  // last layer
  k_gemm<2, false><<<dim3(256, 24), 256, GEMM_LDS, stream>>>(
      Hbf, HPL, lastT, LASTPL, nullptr, 1536, qbuf, kmid, vTl);
  k_attn_fused<<<dim3(256), 512, 65536, stream>>>(
      qbuf, kmid, vTl, head_mask, Hbf, HPL, Hy, ln1_g + 11 * 128, ln1_b + 11 * 128);
  k_mlpf<true><<<dim3(1024), 256, MLPF_LDS, stream>>>(
      Hy, W1T + (size_t)11 * 65536, W1PL, mlp_b1 + 11 * 512,
      W2T + (size_t)11 * 65536, W2PL, mlp_b2 + 11 * 128,
      Hbf, HPL, Hh, ln2_g + 11 * 128, ln2_b + 11 * 128,
      ro_W, ro_b, (float*)d_out);
}